// Round 1
// baseline (4053.682 us; speedup 1.0000x reference)
//
#include <hip/hip_runtime.h>

#define NN 100000   // nodes
#define NE 1000000  // edges
#define NT 200000   // target edges

// ---------------------------------------------------------------------------
// Generic row-wise GEMM: out[R,C] = act(in[R,K] (+add) ) @ w[K,C] + bias
// Register tile: 4 rows x G cols per thread. TR=64 rows per block.
// EPI==1: out[idx] += 0.5*v  (tea update)
// ---------------------------------------------------------------------------
template<int K, int C, int RELU_IN, int RELU_OUT, int EPI>
__global__ __launch_bounds__(256) void rowgemm(
    const float* __restrict__ in, const float* __restrict__ add,
    const float* __restrict__ w, const float* __restrict__ bias,
    float* __restrict__ out, int R)
{
  constexpr int G  = (C % 6 == 0) ? 6 : 5;
  constexpr int NG = C / G;
  constexpr int TR = 64;
  constexpr int KP = (K % 2 == 0) ? (K + 1) : K;  // odd stride: no LDS bank conflicts
  __shared__ float ws[K * C];
  __shared__ float bs[C];
  __shared__ float ins[TR * KP];
  const int t = threadIdx.x;
  for (int i = t; i < K * C; i += 256) ws[i] = w[i];
  if (t < C) bs[t] = bias ? bias[t] : 0.0f;
  const int r0 = blockIdx.x * TR;
  for (int i = t; i < TR * K; i += 256) {
    int r = i / K, k = i - r * K;
    int rg = r0 + r;
    float v = 0.0f;
    if (rg < R) {
      v = in[(size_t)rg * K + k];
      if (add) v += add[(size_t)rg * K + k];
      if (RELU_IN) v = fmaxf(v, 0.0f);
    }
    ins[r * KP + k] = v;
  }
  __syncthreads();
  if (t < 16 * NG) {
    const int rg = t / NG, cg = t - rg * NG;
    const int c0 = cg * G;
    float acc[4][G];
#pragma unroll
    for (int i = 0; i < 4; i++)
#pragma unroll
      for (int g = 0; g < G; g++) acc[i][g] = bs[c0 + g];
    for (int k = 0; k < K; k++) {
      float rv[4];
#pragma unroll
      for (int i = 0; i < 4; i++) rv[i] = ins[(rg * 4 + i) * KP + k];
#pragma unroll
      for (int g = 0; g < G; g++) {
        float wv = ws[k * C + c0 + g];
#pragma unroll
        for (int i = 0; i < 4; i++) acc[i][g] = fmaf(rv[i], wv, acc[i][g]);
      }
    }
#pragma unroll
    for (int i = 0; i < 4; i++) {
      int r = r0 + rg * 4 + i;
      if (r < R) {
#pragma unroll
        for (int g = 0; g < G; g++) {
          float v = acc[i][g];
          if (RELU_OUT) v = fmaxf(v, 0.0f);
          size_t idx = (size_t)r * C + c0 + g;
          if (EPI == 1) out[idx] += 0.5f * v;
          else out[idx] = v;
        }
      }
    }
  }
}

// ---------------------------------------------------------------------------
// GINE message+scatter: per edge e: ea = edge_attr[e]@edge_w + edge_b (on the
// fly), msg = relu(h[src]+ea), atomicAdd into aggr[dst]. 64 edges per block.
// ---------------------------------------------------------------------------
__global__ __launch_bounds__(256) void scatter_msg(
    const float* __restrict__ eattr, const int* __restrict__ ei,
    const float* __restrict__ ew, const float* __restrict__ eb,
    const float* __restrict__ h, float* __restrict__ aggr)
{
  constexpr int TE = 64;
  __shared__ float ws[32 * 66];
  __shared__ float bs[66];
  __shared__ float as[TE * 33];   // stride 33: conflict-free
  __shared__ int sidx[TE], didx[TE];
  const int t = threadIdx.x;
  for (int i = t; i < 32 * 66; i += 256) ws[i] = ew[i];
  if (t < 66) bs[t] = eb[t];
  const int e0 = blockIdx.x * TE;
  if (t < TE) { sidx[t] = ei[e0 + t]; didx[t] = ei[NE + e0 + t]; }
  for (int i = t; i < TE * 32; i += 256) {
    int e = i >> 5, k = i & 31;
    as[e * 33 + k] = eattr[(size_t)e0 * 32 + i];
  }
  __syncthreads();
  if (t < 16 * 11) {
    const int eg = t / 11, cg = (t - eg * 11) * 6;
    float acc[4][6];
#pragma unroll
    for (int i = 0; i < 4; i++)
#pragma unroll
      for (int g = 0; g < 6; g++) acc[i][g] = bs[cg + g];
    for (int k = 0; k < 32; k++) {
      float av[4];
#pragma unroll
      for (int i = 0; i < 4; i++) av[i] = as[(eg * 4 + i) * 33 + k];
#pragma unroll
      for (int g = 0; g < 6; g++) {
        float wv = ws[k * 66 + cg + g];
#pragma unroll
        for (int i = 0; i < 4; i++) acc[i][g] = fmaf(av[i], wv, acc[i][g]);
      }
    }
#pragma unroll
    for (int i = 0; i < 4; i++) {
      int e = eg * 4 + i;
      int s = sidx[e], d = didx[e];
      const float* hp = h + (size_t)s * 66 + cg;
      float* ap = aggr + (size_t)d * 66 + cg;
#pragma unroll
      for (int g = 0; g < 6; g++) {
        float v = hp[g] + acc[i][g];
        if (v > 0.0f) atomicAdd(ap + g, v);  // relu: skip non-positive
      }
    }
  }
}

// ---------------------------------------------------------------------------
// BatchNorm stats: per-channel sum and sumsq over N rows (1024-row chunks).
// ---------------------------------------------------------------------------
__global__ __launch_bounds__(256) void bn_stats(const float* __restrict__ z,
                                                float* __restrict__ stat)
{
  const int t = threadIdx.x;
  if (t >= 198) return;
  const int c = t % 66, rs = t / 66;
  const int r0 = blockIdx.x * 1024;
  float s1 = 0.0f, s2 = 0.0f;
  int rend = r0 + 1024; if (rend > NN) rend = NN;
  for (int r = r0 + rs; r < rend; r += 3) {
    float v = z[(size_t)r * 66 + c];
    s1 += v; s2 += v * v;
  }
  atomicAdd(&stat[c], s1);
  atomicAdd(&stat[66 + c], s2);
}

__global__ __launch_bounds__(256) void bn_update(
    float* __restrict__ h, const float* __restrict__ z,
    const float* __restrict__ stat,
    const float* __restrict__ gamma, const float* __restrict__ beta)
{
  int idx = blockIdx.x * 256 + threadIdx.x;
  if (idx >= NN * 66) return;
  int c = idx % 66;
  float mean = stat[c] * (1.0f / NN);
  float var  = stat[66 + c] * (1.0f / NN) - mean * mean;  // biased, = jnp.var
  float inv  = rsqrtf(var + 1e-5f);
  float zn   = (z[idx] - mean) * inv * gamma[c] + beta[c];
  h[idx] = 0.5f * (h[idx] + fmaxf(zn, 0.0f));
}

// ---------------------------------------------------------------------------
// Q[e,c] = relu(P1[ts[e],c] + P2[td[e],c] + Q[e,c])   (in place)
// ---------------------------------------------------------------------------
template<int C>
__global__ __launch_bounds__(256) void gather_add_relu(
    const float* __restrict__ P1, const float* __restrict__ P2,
    float* __restrict__ Q, const int* __restrict__ eli)
{
  int idx = blockIdx.x * 256 + threadIdx.x;
  if (idx >= NT * C) return;
  int e = idx / C, c = idx - e * C;
  int s = eli[e], d = eli[NT + e];
  float v = P1[(size_t)s * C + c] + P2[(size_t)d * C + c] + Q[idx];
  Q[idx] = fmaxf(v, 0.0f);
}

// ---------------------------------------------------------------------------
// Final small MLP: o1[ET,50] -> relu(o1@w2+b2)[25] -> @w3+b3 -> out[ET,2]
// ---------------------------------------------------------------------------
__global__ __launch_bounds__(256) void final_tail(
    const float* __restrict__ o1, const float* __restrict__ w2,
    const float* __restrict__ b2, const float* __restrict__ w3,
    const float* __restrict__ b3, float* __restrict__ out)
{
  __shared__ float w2s[50 * 25], w3s[25 * 2], b2s[25], b3s[2];
  __shared__ float o1s[64 * 50], o2s[64 * 25];
  const int t = threadIdx.x;
  for (int i = t; i < 50 * 25; i += 256) w2s[i] = w2[i];
  if (t < 50) w3s[t] = w3[t];
  if (t < 25) b2s[t] = b2[t];
  if (t < 2)  b3s[t] = b3[t];
  const int e0 = blockIdx.x * 64;
  for (int i = t; i < 64 * 50; i += 256) o1s[i] = o1[(size_t)e0 * 50 + i];
  __syncthreads();
  for (int it = t; it < 64 * 25; it += 256) {
    int e = it / 25, c = it - e * 25;
    float acc = b2s[c];
    for (int k = 0; k < 50; k++) acc = fmaf(o1s[e * 50 + k], w2s[k * 25 + c], acc);
    o2s[e * 25 + c] = fmaxf(acc, 0.0f);
  }
  __syncthreads();
  if (t < 128) {
    int e = t >> 1, c = t & 1;
    float acc = b3s[c];
    for (int k = 0; k < 25; k++) acc = fmaf(o2s[e * 25 + k], w3s[k * 2 + c], acc);
    out[(size_t)(e0 + e) * 2 + c] = acc;
  }
}

// ---------------------------------------------------------------------------
extern "C" void kernel_launch(void* const* d_in, const int* in_sizes, int n_in,
                              void* d_out, int out_size, void* d_ws, size_t ws_size,
                              hipStream_t stream) {
  const float* x      = (const float*)d_in[0];
  const int*   ei     = (const int*)  d_in[1];
  const float* eattr  = (const float*)d_in[2];
  const int*   eli    = (const int*)  d_in[3];
  const float* tattr  = (const float*)d_in[4];
  const float* node_w = (const float*)d_in[5];
  const float* node_b = (const float*)d_in[6];
  const float* edge_w = (const float*)d_in[7];
  const float* edge_b = (const float*)d_in[8];
  const float* cw1    = (const float*)d_in[9];
  const float* cb1    = (const float*)d_in[10];
  const float* cw2    = (const float*)d_in[11];
  const float* cb2    = (const float*)d_in[12];
  const float* bng    = (const float*)d_in[13];
  const float* bnb    = (const float*)d_in[14];
  const float* ew1    = (const float*)d_in[15];
  const float* eb1    = (const float*)d_in[16];
  const float* ew2    = (const float*)d_in[17];
  const float* eb2    = (const float*)d_in[18];
  const float* mw1    = (const float*)d_in[19];
  const float* mb1    = (const float*)d_in[20];
  const float* mw2    = (const float*)d_in[21];
  const float* mb2    = (const float*)d_in[22];
  const float* mw3    = (const float*)d_in[23];
  const float* mb3    = (const float*)d_in[24];
  float* out = (float*)d_out;

  // workspace layout (fp32): h | zagg(aggr/z/P1/R1) | aux(mid_n/P2/R2) | tea | q(Q/mid/S/o1) | stat
  float* h    = (float*)d_ws;
  float* zagg = h    + (size_t)NN * 66;
  float* aux  = zagg + (size_t)NN * 66;
  float* tea  = aux  + (size_t)NN * 66;
  float* q    = tea  + (size_t)NT * 66;
  float* stat = q    + (size_t)NT * 66;

  const int gN = (NN + 63) / 64;  // 1563
  const int gT = (NT + 63) / 64;  // 3125

  // embeds
  rowgemm<64,66,0,0,0><<<gN,256,0,stream>>>(x,     nullptr, node_w, node_b, h,   NN);
  rowgemm<32,66,0,0,0><<<gT,256,0,stream>>>(tattr, nullptr, edge_w, edge_b, tea, NT);

  for (int l = 0; l < 2; l++) {
    // GINEConv aggregation
    hipMemsetAsync(zagg, 0, (size_t)NN * 66 * sizeof(float), stream);
    scatter_msg<<<NE/64,256,0,stream>>>(eattr, ei, edge_w, edge_b, h, zagg);
    // node MLP: mid = relu((h+aggr)@w1+b1); z = mid@w2+b2
    rowgemm<66,66,0,1,0><<<gN,256,0,stream>>>(h,   zagg,    cw1 + l*66*66, cb1 + l*66, aux,  NN);
    rowgemm<66,66,0,0,0><<<gN,256,0,stream>>>(aux, nullptr, cw2 + l*66*66, cb2 + l*66, zagg, NN);
    // batchnorm + h update
    hipMemsetAsync(stat, 0, 132 * sizeof(float), stream);
    bn_stats<<<(NN+1023)/1024,256,0,stream>>>(zagg, stat);
    bn_update<<<(NN*66+255)/256,256,0,stream>>>(h, zagg, stat, bng + l*66, bnb + l*66);
    // edge update: mid = relu(h[ts]@W1a + h[td]@W1b + tea@W1c + b1); tea += (mid@w2+b2)/2
    const float* w1l = ew1 + (size_t)l*3*66*66;
    rowgemm<66,66,0,0,0><<<gN,256,0,stream>>>(h,   nullptr, w1l,             nullptr,   zagg, NN);
    rowgemm<66,66,0,0,0><<<gN,256,0,stream>>>(h,   nullptr, w1l + 66*66,     nullptr,   aux,  NN);
    rowgemm<66,66,0,0,0><<<gT,256,0,stream>>>(tea, nullptr, w1l + 2*66*66,   eb1+l*66,  q,    NT);
    gather_add_relu<66><<<(NT*66+255)/256,256,0,stream>>>(zagg, aux, q, eli);
    rowgemm<66,66,0,0,1><<<gT,256,0,stream>>>(q,   nullptr, ew2 + l*66*66,   eb2+l*66,  tea,  NT);
  }

  // final classifier: o1 = relu(relu(h)[ts]@A + relu(h)[td]@B + tea@C + b1)
  rowgemm<66,50,1,0,0><<<gN,256,0,stream>>>(h,   nullptr, mw1,          nullptr, zagg, NN);
  rowgemm<66,50,1,0,0><<<gN,256,0,stream>>>(h,   nullptr, mw1 + 66*50,  nullptr, aux,  NN);
  rowgemm<66,50,0,0,0><<<gT,256,0,stream>>>(tea, nullptr, mw1 + 132*50, mb1,     q,    NT);
  gather_add_relu<50><<<(NT*50+255)/256,256,0,stream>>>(zagg, aux, q, eli);
  final_tail<<<gT,256,0,stream>>>(q, mw2, mb2, mw3, mb3, out);
}

// Round 2
// 2402.828 us; speedup vs baseline: 1.6870x; 1.6870x over previous
//
#include <hip/hip_runtime.h>

#define NN 100000   // nodes
#define NE 1000000  // edges
#define NT 200000   // target edges

// ---------------------------------------------------------------------------
// Generic row-wise GEMM: out[R,C] = act(in[R,K] (+add) ) @ w[K,C] + bias
// Register tile: 4 rows x G cols per thread. TR=64 rows per block.
// EPI==1: out[idx] += 0.5*v  (tea update)
// ---------------------------------------------------------------------------
template<int K, int C, int RELU_IN, int RELU_OUT, int EPI>
__global__ __launch_bounds__(256) void rowgemm(
    const float* __restrict__ in, const float* __restrict__ add,
    const float* __restrict__ w, const float* __restrict__ bias,
    float* __restrict__ out, int R)
{
  constexpr int G  = (C % 6 == 0) ? 6 : 5;
  constexpr int NG = C / G;
  constexpr int TR = 64;
  constexpr int KP = (K % 2 == 0) ? (K + 1) : K;  // odd stride: no LDS bank conflicts
  __shared__ float ws[K * C];
  __shared__ float bs[C];
  __shared__ float ins[TR * KP];
  const int t = threadIdx.x;
  for (int i = t; i < K * C; i += 256) ws[i] = w[i];
  if (t < C) bs[t] = bias ? bias[t] : 0.0f;
  const int r0 = blockIdx.x * TR;
  for (int i = t; i < TR * K; i += 256) {
    int r = i / K, k = i - r * K;
    int rg = r0 + r;
    float v = 0.0f;
    if (rg < R) {
      v = in[(size_t)rg * K + k];
      if (add) v += add[(size_t)rg * K + k];
      if (RELU_IN) v = fmaxf(v, 0.0f);
    }
    ins[r * KP + k] = v;
  }
  __syncthreads();
  if (t < 16 * NG) {
    const int rg = t / NG, cg = t - rg * NG;
    const int c0 = cg * G;
    float acc[4][G];
#pragma unroll
    for (int i = 0; i < 4; i++)
#pragma unroll
      for (int g = 0; g < G; g++) acc[i][g] = bs[c0 + g];
    for (int k = 0; k < K; k++) {
      float rv[4];
#pragma unroll
      for (int i = 0; i < 4; i++) rv[i] = ins[(rg * 4 + i) * KP + k];
#pragma unroll
      for (int g = 0; g < G; g++) {
        float wv = ws[k * C + c0 + g];
#pragma unroll
        for (int i = 0; i < 4; i++) acc[i][g] = fmaf(rv[i], wv, acc[i][g]);
      }
    }
#pragma unroll
    for (int i = 0; i < 4; i++) {
      int r = r0 + rg * 4 + i;
      if (r < R) {
#pragma unroll
        for (int g = 0; g < G; g++) {
          float v = acc[i][g];
          if (RELU_OUT) v = fmaxf(v, 0.0f);
          size_t idx = (size_t)r * C + c0 + g;
          if (EPI == 1) out[idx] += 0.5f * v;
          else out[idx] = v;
        }
      }
    }
  }
}

// ---------------------------------------------------------------------------
// CSR build: histogram of dst, prefix scan, fill (sorted-by-dst edge lists).
// ---------------------------------------------------------------------------
__global__ __launch_bounds__(256) void hist_kernel(const int* __restrict__ ei,
                                                   int* __restrict__ deg)
{
  int e = blockIdx.x * 256 + threadIdx.x;
  if (e < NE) atomicAdd(&deg[ei[NE + e]], 1);
}

__global__ __launch_bounds__(1024) void scan_kernel(const int* __restrict__ deg,
                                                    int* __restrict__ rowptr)
{
  __shared__ int sums[1024];
  const int t = threadIdx.x;
  const int CH = (NN + 1023) / 1024;  // 98
  int lo = t * CH, hi = lo + CH;
  if (hi > NN) hi = NN;
  int s = 0;
  for (int i = lo; i < hi; i++) s += deg[i];
  sums[t] = s;
  __syncthreads();
  // Hillis-Steele inclusive scan
  for (int off = 1; off < 1024; off <<= 1) {
    int v = (t >= off) ? sums[t - off] : 0;
    __syncthreads();
    sums[t] += v;
    __syncthreads();
  }
  int run = (t == 0) ? 0 : sums[t - 1];  // exclusive offset for this chunk
  for (int i = lo; i < hi; i++) { rowptr[i] = run; run += deg[i]; }
  if (t == 1023) rowptr[NN] = run;  // == NE
}

__global__ __launch_bounds__(256) void fill_kernel(
    const int* __restrict__ ei, const int* __restrict__ rowptr,
    int* __restrict__ cur, int* __restrict__ srcS, int* __restrict__ permS)
{
  int e = blockIdx.x * 256 + threadIdx.x;
  if (e >= NE) return;
  int d = ei[NE + e];
  int pos = atomicAdd(&cur[d], 1);
  int w = rowptr[d] + pos;
  srcS[w] = ei[e];
  permS[w] = e;
}

// ---------------------------------------------------------------------------
// GINE aggregation, gather form. Thread = (node, channel). Weight column
// ew[:,c] hoisted to 32 registers; per edge: 8 float4 broadcast loads of the
// edge_attr row + 32 FMA + 1 coalesced h load. No atomics, no LDS.
//   aggr[n,c] = sum_{e in CSR[n]} relu( h[src_e, c] + eb[c] + edge_attr[e,:]@ew[:,c] )
// ---------------------------------------------------------------------------
__global__ __launch_bounds__(256) void aggregate(
    const int* __restrict__ rowptr, const int* __restrict__ srcS,
    const int* __restrict__ permS, const float* __restrict__ eattr,
    const float* __restrict__ ew, const float* __restrict__ eb,
    const float* __restrict__ h, float* __restrict__ aggr)
{
  int idx = blockIdx.x * 256 + threadIdx.x;
  if (idx >= NN * 66) return;
  int n = idx / 66, c = idx - n * 66;
  float wc[32];
#pragma unroll
  for (int k = 0; k < 32; k++) wc[k] = ew[k * 66 + c];
  const float bc = eb[c];
  const int e0 = rowptr[n], e1 = rowptr[n + 1];
  float acc = 0.0f;
  for (int i = e0; i < e1; i++) {
    int p = permS[i], s = srcS[i];
    const float4* ar = (const float4*)(eattr + (size_t)p * 32);
    float m = bc + h[(size_t)s * 66 + c];
#pragma unroll
    for (int j = 0; j < 8; j++) {
      float4 a = ar[j];
      m = fmaf(a.x, wc[4 * j + 0], m);
      m = fmaf(a.y, wc[4 * j + 1], m);
      m = fmaf(a.z, wc[4 * j + 2], m);
      m = fmaf(a.w, wc[4 * j + 3], m);
    }
    acc += fmaxf(m, 0.0f);
  }
  aggr[idx] = acc;
}

// ---------------------------------------------------------------------------
// BatchNorm stats: per-channel sum and sumsq over N rows (1024-row chunks).
// ---------------------------------------------------------------------------
__global__ __launch_bounds__(256) void bn_stats(const float* __restrict__ z,
                                                float* __restrict__ stat)
{
  const int t = threadIdx.x;
  if (t >= 198) return;
  const int c = t % 66, rs = t / 66;
  const int r0 = blockIdx.x * 1024;
  float s1 = 0.0f, s2 = 0.0f;
  int rend = r0 + 1024; if (rend > NN) rend = NN;
  for (int r = r0 + rs; r < rend; r += 3) {
    float v = z[(size_t)r * 66 + c];
    s1 += v; s2 += v * v;
  }
  atomicAdd(&stat[c], s1);
  atomicAdd(&stat[66 + c], s2);
}

__global__ __launch_bounds__(256) void bn_update(
    float* __restrict__ h, const float* __restrict__ z,
    const float* __restrict__ stat,
    const float* __restrict__ gamma, const float* __restrict__ beta)
{
  int idx = blockIdx.x * 256 + threadIdx.x;
  if (idx >= NN * 66) return;
  int c = idx % 66;
  float mean = stat[c] * (1.0f / NN);
  float var  = stat[66 + c] * (1.0f / NN) - mean * mean;  // biased, = jnp.var
  float inv  = rsqrtf(var + 1e-5f);
  float zn   = (z[idx] - mean) * inv * gamma[c] + beta[c];
  h[idx] = 0.5f * (h[idx] + fmaxf(zn, 0.0f));
}

// ---------------------------------------------------------------------------
// Q[e,c] = relu(P1[ts[e],c] + P2[td[e],c] + Q[e,c])   (in place)
// ---------------------------------------------------------------------------
template<int C>
__global__ __launch_bounds__(256) void gather_add_relu(
    const float* __restrict__ P1, const float* __restrict__ P2,
    float* __restrict__ Q, const int* __restrict__ eli)
{
  int idx = blockIdx.x * 256 + threadIdx.x;
  if (idx >= NT * C) return;
  int e = idx / C, c = idx - e * C;
  int s = eli[e], d = eli[NT + e];
  float v = P1[(size_t)s * C + c] + P2[(size_t)d * C + c] + Q[idx];
  Q[idx] = fmaxf(v, 0.0f);
}

// ---------------------------------------------------------------------------
// Final small MLP: o1[ET,50] -> relu(o1@w2+b2)[25] -> @w3+b3 -> out[ET,2]
// ---------------------------------------------------------------------------
__global__ __launch_bounds__(256) void final_tail(
    const float* __restrict__ o1, const float* __restrict__ w2,
    const float* __restrict__ b2, const float* __restrict__ w3,
    const float* __restrict__ b3, float* __restrict__ out)
{
  __shared__ float w2s[50 * 25], w3s[25 * 2], b2s[25], b3s[2];
  __shared__ float o1s[64 * 50], o2s[64 * 25];
  const int t = threadIdx.x;
  for (int i = t; i < 50 * 25; i += 256) w2s[i] = w2[i];
  if (t < 50) w3s[t] = w3[t];
  if (t < 25) b2s[t] = b2[t];
  if (t < 2)  b3s[t] = b3[t];
  const int e0 = blockIdx.x * 64;
  for (int i = t; i < 64 * 50; i += 256) o1s[i] = o1[(size_t)e0 * 50 + i];
  __syncthreads();
  for (int it = t; it < 64 * 25; it += 256) {
    int e = it / 25, c = it - e * 25;
    float acc = b2s[c];
    for (int k = 0; k < 50; k++) acc = fmaf(o1s[e * 50 + k], w2s[k * 25 + c], acc);
    o2s[e * 25 + c] = fmaxf(acc, 0.0f);
  }
  __syncthreads();
  if (t < 128) {
    int e = t >> 1, c = t & 1;
    float acc = b3s[c];
    for (int k = 0; k < 25; k++) acc = fmaf(o2s[e * 25 + k], w3s[k * 2 + c], acc);
    out[(size_t)(e0 + e) * 2 + c] = acc;
  }
}

// ---------------------------------------------------------------------------
extern "C" void kernel_launch(void* const* d_in, const int* in_sizes, int n_in,
                              void* d_out, int out_size, void* d_ws, size_t ws_size,
                              hipStream_t stream) {
  const float* x      = (const float*)d_in[0];
  const int*   ei     = (const int*)  d_in[1];
  const float* eattr  = (const float*)d_in[2];
  const int*   eli    = (const int*)  d_in[3];
  const float* tattr  = (const float*)d_in[4];
  const float* node_w = (const float*)d_in[5];
  const float* node_b = (const float*)d_in[6];
  const float* edge_w = (const float*)d_in[7];
  const float* edge_b = (const float*)d_in[8];
  const float* cw1    = (const float*)d_in[9];
  const float* cb1    = (const float*)d_in[10];
  const float* cw2    = (const float*)d_in[11];
  const float* cb2    = (const float*)d_in[12];
  const float* bng    = (const float*)d_in[13];
  const float* bnb    = (const float*)d_in[14];
  const float* ew1    = (const float*)d_in[15];
  const float* eb1    = (const float*)d_in[16];
  const float* ew2    = (const float*)d_in[17];
  const float* eb2    = (const float*)d_in[18];
  const float* mw1    = (const float*)d_in[19];
  const float* mb1    = (const float*)d_in[20];
  const float* mw2    = (const float*)d_in[21];
  const float* mb2    = (const float*)d_in[22];
  const float* mw3    = (const float*)d_in[23];
  const float* mb3    = (const float*)d_in[24];
  float* out = (float*)d_out;

  // workspace layout (fp32/int32):
  // h | zagg(aggr/z/P1) | aux(mid/P2) | tea | q(Q/o1) | stat | rowptr | cur | srcS | permS
  float* h      = (float*)d_ws;
  float* zagg   = h    + (size_t)NN * 66;
  float* aux    = zagg + (size_t)NN * 66;
  float* tea    = aux  + (size_t)NN * 66;
  float* q      = tea  + (size_t)NT * 66;
  float* stat   = q    + (size_t)NT * 66;
  int*   rowptr = (int*)(stat + 256);
  int*   cur    = rowptr + (NN + 1);
  int*   srcS   = cur + NN;
  int*   permS  = srcS + NE;

  const int gN = (NN + 63) / 64;  // 1563
  const int gT = (NT + 63) / 64;  // 3125

  // ---- CSR build (once; edge_index identical every call) ----
  hipMemsetAsync(cur, 0, (size_t)NN * sizeof(int), stream);
  hist_kernel<<<(NE + 255) / 256, 256, 0, stream>>>(ei, cur);
  scan_kernel<<<1, 1024, 0, stream>>>(cur, rowptr);
  hipMemsetAsync(cur, 0, (size_t)NN * sizeof(int), stream);
  fill_kernel<<<(NE + 255) / 256, 256, 0, stream>>>(ei, rowptr, cur, srcS, permS);

  // embeds
  rowgemm<64,66,0,0,0><<<gN,256,0,stream>>>(x,     nullptr, node_w, node_b, h,   NN);
  rowgemm<32,66,0,0,0><<<gT,256,0,stream>>>(tattr, nullptr, edge_w, edge_b, tea, NT);

  for (int l = 0; l < 2; l++) {
    // GINEConv aggregation (gather, deterministic, no atomics)
    aggregate<<<(NN * 66 + 255) / 256, 256, 0, stream>>>(
        rowptr, srcS, permS, eattr, edge_w, edge_b, h, zagg);
    // node MLP: mid = relu((h+aggr)@w1+b1); z = mid@w2+b2
    rowgemm<66,66,0,1,0><<<gN,256,0,stream>>>(h,   zagg,    cw1 + l*66*66, cb1 + l*66, aux,  NN);
    rowgemm<66,66,0,0,0><<<gN,256,0,stream>>>(aux, nullptr, cw2 + l*66*66, cb2 + l*66, zagg, NN);
    // batchnorm + h update
    hipMemsetAsync(stat, 0, 132 * sizeof(float), stream);
    bn_stats<<<(NN+1023)/1024,256,0,stream>>>(zagg, stat);
    bn_update<<<(NN*66+255)/256,256,0,stream>>>(h, zagg, stat, bng + l*66, bnb + l*66);
    // edge update: mid = relu(h[ts]@W1a + h[td]@W1b + tea@W1c + b1); tea += (mid@w2+b2)/2
    const float* w1l = ew1 + (size_t)l*3*66*66;
    rowgemm<66,66,0,0,0><<<gN,256,0,stream>>>(h,   nullptr, w1l,             nullptr,   zagg, NN);
    rowgemm<66,66,0,0,0><<<gN,256,0,stream>>>(h,   nullptr, w1l + 66*66,     nullptr,   aux,  NN);
    rowgemm<66,66,0,0,0><<<gT,256,0,stream>>>(tea, nullptr, w1l + 2*66*66,   eb1+l*66,  q,    NT);
    gather_add_relu<66><<<(NT*66+255)/256,256,0,stream>>>(zagg, aux, q, eli);
    rowgemm<66,66,0,0,1><<<gT,256,0,stream>>>(q,   nullptr, ew2 + l*66*66,   eb2+l*66,  tea,  NT);
  }

  // final classifier: o1 = relu(relu(h)[ts]@A + relu(h)[td]@B + tea@C + b1)
  rowgemm<66,50,1,0,0><<<gN,256,0,stream>>>(h,   nullptr, mw1,          nullptr, zagg, NN);
  rowgemm<66,50,1,0,0><<<gN,256,0,stream>>>(h,   nullptr, mw1 + 66*50,  nullptr, aux,  NN);
  rowgemm<66,50,0,0,0><<<gT,256,0,stream>>>(tea, nullptr, mw1 + 132*50, mb1,     q,    NT);
  gather_add_relu<50><<<(NT*50+255)/256,256,0,stream>>>(zagg, aux, q, eli);
  final_tail<<<gT,256,0,stream>>>(q, mw2, mb2, mw3, mb3, out);
}

// Round 3
// 1902.305 us; speedup vs baseline: 2.1309x; 1.2631x over previous
//
#include <hip/hip_runtime.h>

#define NN 100000   // nodes
#define NE 1000000  // edges (divisible by 64)
#define NT 200000   // target edges (divisible by 64)

// ---------------------------------------------------------------------------
// Generic row-wise GEMM: out[R,C] = act(in[R,K] (+add) ) @ w[K,C] + bias
// Register tile: 4 rows x G cols per thread. TR=64 rows per block.
// ---------------------------------------------------------------------------
template<int K, int C, int RELU_IN, int RELU_OUT>
__global__ __launch_bounds__(256) void rowgemm(
    const float* __restrict__ in, const float* __restrict__ add,
    const float* __restrict__ w, const float* __restrict__ bias,
    float* __restrict__ out, int R)
{
  constexpr int G  = (C % 6 == 0) ? 6 : 5;
  constexpr int NG = C / G;
  constexpr int TR = 64;
  constexpr int KP = (K % 2 == 0) ? (K + 1) : K;  // odd stride: no LDS bank conflicts
  __shared__ float ws[K * C];
  __shared__ float bs[C];
  __shared__ float ins[TR * KP];
  const int t = threadIdx.x;
  for (int i = t; i < K * C; i += 256) ws[i] = w[i];
  if (t < C) bs[t] = bias ? bias[t] : 0.0f;
  const int r0 = blockIdx.x * TR;
  for (int i = t; i < TR * K; i += 256) {
    int r = i / K, k = i - r * K;
    int rg = r0 + r;
    float v = 0.0f;
    if (rg < R) {
      v = in[(size_t)rg * K + k];
      if (add) v += add[(size_t)rg * K + k];
      if (RELU_IN) v = fmaxf(v, 0.0f);
    }
    ins[r * KP + k] = v;
  }
  __syncthreads();
  if (t < 16 * NG) {
    const int rg = t / NG, cg = t - rg * NG;
    const int c0 = cg * G;
    float acc[4][G];
#pragma unroll
    for (int i = 0; i < 4; i++)
#pragma unroll
      for (int g = 0; g < G; g++) acc[i][g] = bs[c0 + g];
    for (int k = 0; k < K; k++) {
      float rv[4];
#pragma unroll
      for (int i = 0; i < 4; i++) rv[i] = ins[(rg * 4 + i) * KP + k];
#pragma unroll
      for (int g = 0; g < G; g++) {
        float wv = ws[k * C + c0 + g];
#pragma unroll
        for (int i = 0; i < 4; i++) acc[i][g] = fmaf(rv[i], wv, acc[i][g]);
      }
    }
#pragma unroll
    for (int i = 0; i < 4; i++) {
      int r = r0 + rg * 4 + i;
      if (r < R) {
#pragma unroll
        for (int g = 0; g < G; g++) {
          float v = acc[i][g];
          if (RELU_OUT) v = fmaxf(v, 0.0f);
          out[(size_t)r * C + c0 + g] = v;
        }
      }
    }
  }
}

// ---------------------------------------------------------------------------
// CSR build: histogram of dst, prefix scan, fill (sorted-by-dst edge lists).
// ---------------------------------------------------------------------------
__global__ __launch_bounds__(256) void hist_kernel(const int* __restrict__ ei,
                                                   int* __restrict__ deg)
{
  int e = blockIdx.x * 256 + threadIdx.x;
  if (e < NE) atomicAdd(&deg[ei[NE + e]], 1);
}

__global__ __launch_bounds__(1024) void scan_kernel(const int* __restrict__ deg,
                                                    int* __restrict__ rowptr)
{
  __shared__ int sums[1024];
  const int t = threadIdx.x;
  const int CH = (NN + 1023) / 1024;  // 98
  int lo = t * CH, hi = lo + CH;
  if (hi > NN) hi = NN;
  int s = 0;
  for (int i = lo; i < hi; i++) s += deg[i];
  sums[t] = s;
  __syncthreads();
  for (int off = 1; off < 1024; off <<= 1) {
    int v = (t >= off) ? sums[t - off] : 0;
    __syncthreads();
    sums[t] += v;
    __syncthreads();
  }
  int run = (t == 0) ? 0 : sums[t - 1];
  for (int i = lo; i < hi; i++) { rowptr[i] = run; run += deg[i]; }
  if (t == 1023) rowptr[NN] = run;  // == NE
}

__global__ __launch_bounds__(256) void fill_kernel(
    const int* __restrict__ ei, const int* __restrict__ rowptr,
    int* __restrict__ cur, int* __restrict__ srcS, int* __restrict__ dstS,
    int* __restrict__ permS)
{
  int e = blockIdx.x * 256 + threadIdx.x;
  if (e >= NE) return;
  int d = ei[NE + e];
  int pos = atomicAdd(&cur[d], 1);
  int w = rowptr[d] + pos;
  srcS[w] = ei[e];
  dstS[w] = d;
  permS[w] = e;
}

// ---------------------------------------------------------------------------
// Fused GINE message + aggregation over dst-sorted edges.
// Block = 64 edges. Stage edge_attr rows in LDS (fetched once), register-tile
// GEMM (ea@ew), add gathered h[src] + bias, relu -> LDS msg tile; then a
// 66-thread per-channel segment-sum over the contiguous dst runs. Interior
// nodes: direct store. Block-boundary nodes: atomicAdd (aggr pre-zeroed).
// ---------------------------------------------------------------------------
__global__ __launch_bounds__(256) void msg_aggr(
    const int* __restrict__ rowptr, const int* __restrict__ srcS,
    const int* __restrict__ dstS, const int* __restrict__ permS,
    const float* __restrict__ eattr, const float* __restrict__ ew,
    const float* __restrict__ eb, const float* __restrict__ h,
    float* __restrict__ aggr)
{
  __shared__ float ws[32 * 66];
  __shared__ float bs[66];
  __shared__ float as[64 * 33];   // stride 33: conflict-free
  __shared__ float msgS[64 * 67]; // stride 67: conflict-free
  __shared__ int sidx[64], didx[64];
  const int t = threadIdx.x;
  const int e0 = blockIdx.x * 64;
  for (int i = t; i < 32 * 66; i += 256) ws[i] = ew[i];
  if (t < 66) bs[t] = eb[t];
  if (t < 64) { sidx[t] = srcS[e0 + t]; didx[t] = dstS[e0 + t]; }
  for (int i = t; i < 64 * 32; i += 256) {
    int e = i >> 5, k = i & 31;
    int p = permS[e0 + e];
    as[e * 33 + k] = eattr[(size_t)p * 32 + k];
  }
  __syncthreads();
  if (t < 176) {
    const int eg = t / 11, cg = (t - eg * 11) * 6;
    float acc[4][6];
#pragma unroll
    for (int i = 0; i < 4; i++)
#pragma unroll
      for (int g = 0; g < 6; g++) acc[i][g] = bs[cg + g];
    for (int k = 0; k < 32; k++) {
      float av[4];
#pragma unroll
      for (int i = 0; i < 4; i++) av[i] = as[(eg * 4 + i) * 33 + k];
#pragma unroll
      for (int g = 0; g < 6; g++) {
        float wv = ws[k * 66 + cg + g];
#pragma unroll
        for (int i = 0; i < 4; i++) acc[i][g] = fmaf(av[i], wv, acc[i][g]);
      }
    }
#pragma unroll
    for (int i = 0; i < 4; i++) {
      int e = eg * 4 + i;
      const float* hp = h + (size_t)sidx[e] * 66 + cg;
#pragma unroll
      for (int g = 0; g < 6; g++)
        msgS[e * 67 + cg + g] = fmaxf(acc[i][g] + hp[g], 0.0f);
    }
  }
  __syncthreads();
  if (t < 66) {
    const int nfirst = didx[0], nlast = didx[63];
    const bool fp = rowptr[nfirst] < e0;          // first node continues left
    const bool lp = rowptr[nlast + 1] > e0 + 64;  // last node continues right
    float acc = 0.0f;
    for (int e = 0; e < 64; e++) {
      acc += msgS[e * 67 + t];
      bool bound = (e == 63) || (didx[e + 1] != didx[e]);
      if (bound) {
        int n = didx[e];
        if ((n == nfirst && fp) || (n == nlast && lp))
          atomicAdd(&aggr[(size_t)n * 66 + t], acc);
        else
          aggr[(size_t)n * 66 + t] = acc;
        acc = 0.0f;
      }
    }
  }
}

// ---------------------------------------------------------------------------
// BatchNorm stats + update
// ---------------------------------------------------------------------------
__global__ __launch_bounds__(256) void bn_stats(const float* __restrict__ z,
                                                float* __restrict__ stat)
{
  const int t = threadIdx.x;
  if (t >= 198) return;
  const int c = t % 66, rs = t / 66;
  const int r0 = blockIdx.x * 1024;
  float s1 = 0.0f, s2 = 0.0f;
  int rend = r0 + 1024; if (rend > NN) rend = NN;
  for (int r = r0 + rs; r < rend; r += 3) {
    float v = z[(size_t)r * 66 + c];
    s1 += v; s2 += v * v;
  }
  atomicAdd(&stat[c], s1);
  atomicAdd(&stat[66 + c], s2);
}

__global__ __launch_bounds__(256) void bn_update(
    float* __restrict__ h, const float* __restrict__ z,
    const float* __restrict__ stat,
    const float* __restrict__ gamma, const float* __restrict__ beta)
{
  int idx = blockIdx.x * 256 + threadIdx.x;
  if (idx >= NN * 66) return;
  int c = idx % 66;
  float mean = stat[c] * (1.0f / NN);
  float var  = stat[66 + c] * (1.0f / NN) - mean * mean;  // biased, = jnp.var
  float inv  = rsqrtf(var + 1e-5f);
  float zn   = (z[idx] - mean) * inv * gamma[c] + beta[c];
  h[idx] = 0.5f * (h[idx] + fmaxf(zn, 0.0f));
}

// ---------------------------------------------------------------------------
// Fused per-layer edge update over 64 target-edge tiles:
//   mid = relu( tea@W1c + b1 + P1[ts] + P2[td] );  tea += 0.5*(mid@W2 + b2)
// mid lives in LDS (reuses the input tile buffer). No global mid round-trip.
// ---------------------------------------------------------------------------
__global__ __launch_bounds__(256) void edge_fused(
    const float* __restrict__ P1, const float* __restrict__ P2,
    const int* __restrict__ eli, const float* __restrict__ w1c,
    const float* __restrict__ b1, const float* __restrict__ w2,
    const float* __restrict__ b2, float* __restrict__ tea)
{
  __shared__ float wsA[66 * 66];
  __shared__ float wsB[66 * 66];
  __shared__ float bsA[66], bsB[66];
  __shared__ float ins[64 * 67];
  __shared__ int sidx[64], didx[64];
  const int t = threadIdx.x;
  const int e0 = blockIdx.x * 64;
  for (int i = t; i < 66 * 66; i += 256) { wsA[i] = w1c[i]; wsB[i] = w2[i]; }
  if (t < 66) { bsA[t] = b1[t]; bsB[t] = b2[t]; }
  if (t < 64) { sidx[t] = eli[e0 + t]; didx[t] = eli[NT + e0 + t]; }
  for (int i = t; i < 64 * 66; i += 256) {
    int r = i / 66, k = i - r * 66;
    ins[r * 67 + k] = tea[(size_t)(e0 + r) * 66 + k];
  }
  __syncthreads();
  const int eg = t / 11, cg = (t - eg * 11) * 6;
  float frag[4][6];
  if (t < 176) {
    float acc[4][6];
#pragma unroll
    for (int i = 0; i < 4; i++)
#pragma unroll
      for (int g = 0; g < 6; g++) acc[i][g] = bsA[cg + g];
    for (int k = 0; k < 66; k++) {
      float rv[4];
#pragma unroll
      for (int i = 0; i < 4; i++) rv[i] = ins[(eg * 4 + i) * 67 + k];
#pragma unroll
      for (int g = 0; g < 6; g++) {
        float wv = wsA[k * 66 + cg + g];
#pragma unroll
        for (int i = 0; i < 4; i++) acc[i][g] = fmaf(rv[i], wv, acc[i][g]);
      }
    }
#pragma unroll
    for (int i = 0; i < 4; i++) {
      int e = eg * 4 + i;
      const float* p1 = P1 + (size_t)sidx[e] * 66 + cg;
      const float* p2 = P2 + (size_t)didx[e] * 66 + cg;
#pragma unroll
      for (int g = 0; g < 6; g++)
        frag[i][g] = fmaxf(acc[i][g] + p1[g] + p2[g], 0.0f);
    }
  }
  __syncthreads();
  if (t < 176) {
#pragma unroll
    for (int i = 0; i < 4; i++)
#pragma unroll
      for (int g = 0; g < 6; g++) ins[(eg * 4 + i) * 67 + cg + g] = frag[i][g];
  }
  __syncthreads();
  if (t < 176) {
    float acc[4][6];
#pragma unroll
    for (int i = 0; i < 4; i++)
#pragma unroll
      for (int g = 0; g < 6; g++) acc[i][g] = bsB[cg + g];
    for (int k = 0; k < 66; k++) {
      float rv[4];
#pragma unroll
      for (int i = 0; i < 4; i++) rv[i] = ins[(eg * 4 + i) * 67 + k];
#pragma unroll
      for (int g = 0; g < 6; g++) {
        float wv = wsB[k * 66 + cg + g];
#pragma unroll
        for (int i = 0; i < 4; i++) acc[i][g] = fmaf(rv[i], wv, acc[i][g]);
      }
    }
#pragma unroll
    for (int i = 0; i < 4; i++) {
      size_t base = (size_t)(e0 + eg * 4 + i) * 66 + cg;
#pragma unroll
      for (int g = 0; g < 6; g++) tea[base + g] += 0.5f * acc[i][g];
    }
  }
}

// ---------------------------------------------------------------------------
// Fused final classifier over 64 target-edge tiles:
//   o1 = relu( tea@C + b1 + P1[ts] + P2[td] )   (P1/P2 = relu(h)@A / @B)
//   o2 = relu( o1@w2 + b2 );  out = o2@w3 + b3
// ---------------------------------------------------------------------------
__global__ __launch_bounds__(256) void final_fused(
    const float* __restrict__ tea, const float* __restrict__ P1,
    const float* __restrict__ P2, const int* __restrict__ eli,
    const float* __restrict__ w1c, const float* __restrict__ b1,
    const float* __restrict__ w2, const float* __restrict__ b2,
    const float* __restrict__ w3, const float* __restrict__ b3,
    float* __restrict__ out)
{
  __shared__ float wsA[66 * 50];
  __shared__ float w2s[50 * 25], w3s[25 * 2];
  __shared__ float b1s[50], b2s[25], b3s[2];
  __shared__ float ins[64 * 67];
  __shared__ float o1s[64 * 51];
  __shared__ float o2s[64 * 25];
  __shared__ int sidx[64], didx[64];
  const int t = threadIdx.x;
  const int e0 = blockIdx.x * 64;
  for (int i = t; i < 66 * 50; i += 256) wsA[i] = w1c[i];
  for (int i = t; i < 50 * 25; i += 256) w2s[i] = w2[i];
  if (t < 50) { w3s[t] = w3[t]; b1s[t] = b1[t]; }
  if (t < 25) b2s[t] = b2[t];
  if (t < 2)  b3s[t] = b3[t];
  if (t < 64) { sidx[t] = eli[e0 + t]; didx[t] = eli[NT + e0 + t]; }
  for (int i = t; i < 64 * 66; i += 256) {
    int r = i / 66, k = i - r * 66;
    ins[r * 67 + k] = tea[(size_t)(e0 + r) * 66 + k];
  }
  __syncthreads();
  if (t < 160) {
    const int rg = t / 10, cg = t - rg * 10;
    const int c0 = cg * 5;
    float acc[4][5];
#pragma unroll
    for (int i = 0; i < 4; i++)
#pragma unroll
      for (int g = 0; g < 5; g++) acc[i][g] = b1s[c0 + g];
    for (int k = 0; k < 66; k++) {
      float rv[4];
#pragma unroll
      for (int i = 0; i < 4; i++) rv[i] = ins[(rg * 4 + i) * 67 + k];
#pragma unroll
      for (int g = 0; g < 5; g++) {
        float wv = wsA[k * 50 + c0 + g];
#pragma unroll
        for (int i = 0; i < 4; i++) acc[i][g] = fmaf(rv[i], wv, acc[i][g]);
      }
    }
#pragma unroll
    for (int i = 0; i < 4; i++) {
      int e = rg * 4 + i;
      const float* p1 = P1 + (size_t)sidx[e] * 50 + c0;
      const float* p2 = P2 + (size_t)didx[e] * 50 + c0;
#pragma unroll
      for (int g = 0; g < 5; g++)
        o1s[e * 51 + c0 + g] = fmaxf(acc[i][g] + p1[g] + p2[g], 0.0f);
    }
  }
  __syncthreads();
  for (int it = t; it < 64 * 25; it += 256) {
    int e = it / 25, c = it - e * 25;
    float acc = b2s[c];
    for (int k = 0; k < 50; k++) acc = fmaf(o1s[e * 51 + k], w2s[k * 25 + c], acc);
    o2s[e * 25 + c] = fmaxf(acc, 0.0f);
  }
  __syncthreads();
  if (t < 128) {
    int e = t >> 1, c = t & 1;
    float acc = b3s[c];
    for (int k = 0; k < 25; k++) acc = fmaf(o2s[e * 25 + k], w3s[k * 2 + c], acc);
    out[(size_t)(e0 + e) * 2 + c] = acc;
  }
}

// ---------------------------------------------------------------------------
extern "C" void kernel_launch(void* const* d_in, const int* in_sizes, int n_in,
                              void* d_out, int out_size, void* d_ws, size_t ws_size,
                              hipStream_t stream) {
  const float* x      = (const float*)d_in[0];
  const int*   ei     = (const int*)  d_in[1];
  const float* eattr  = (const float*)d_in[2];
  const int*   eli    = (const int*)  d_in[3];
  const float* tattr  = (const float*)d_in[4];
  const float* node_w = (const float*)d_in[5];
  const float* node_b = (const float*)d_in[6];
  const float* edge_w = (const float*)d_in[7];
  const float* edge_b = (const float*)d_in[8];
  const float* cw1    = (const float*)d_in[9];
  const float* cb1    = (const float*)d_in[10];
  const float* cw2    = (const float*)d_in[11];
  const float* cb2    = (const float*)d_in[12];
  const float* bng    = (const float*)d_in[13];
  const float* bnb    = (const float*)d_in[14];
  const float* ew1    = (const float*)d_in[15];
  const float* eb1    = (const float*)d_in[16];
  const float* ew2    = (const float*)d_in[17];
  const float* eb2    = (const float*)d_in[18];
  const float* mw1    = (const float*)d_in[19];
  const float* mb1    = (const float*)d_in[20];
  const float* mw2    = (const float*)d_in[21];
  const float* mb2    = (const float*)d_in[22];
  const float* mw3    = (const float*)d_in[23];
  const float* mb3    = (const float*)d_in[24];
  float* out = (float*)d_out;

  // workspace: h | buf1 | buf2 | tea | stat | rowptr | cur | srcS | dstS | permS
  float* h      = (float*)d_ws;
  float* buf1   = h    + (size_t)NN * 66;
  float* buf2   = buf1 + (size_t)NN * 66;
  float* tea    = buf2 + (size_t)NN * 66;
  float* stat   = tea  + (size_t)NT * 66;
  int*   rowptr = (int*)(stat + 256);
  int*   cur    = rowptr + (NN + 1);
  int*   srcS   = cur + NN;
  int*   dstS   = srcS + NE;
  int*   permS  = dstS + NE;

  const int gN = (NN + 63) / 64;  // 1563
  const int gT = NT / 64;         // 3125
  const int gE = NE / 64;         // 15625

  // ---- CSR build ----
  hipMemsetAsync(cur, 0, (size_t)NN * sizeof(int), stream);
  hist_kernel<<<(NE + 255) / 256, 256, 0, stream>>>(ei, cur);
  scan_kernel<<<1, 1024, 0, stream>>>(cur, rowptr);
  hipMemsetAsync(cur, 0, (size_t)NN * sizeof(int), stream);
  fill_kernel<<<(NE + 255) / 256, 256, 0, stream>>>(ei, rowptr, cur, srcS, dstS, permS);

  // ---- embeds ----
  rowgemm<64,66,0,0><<<gN,256,0,stream>>>(x,     nullptr, node_w, node_b, h,   NN);
  rowgemm<32,66,0,0><<<gT,256,0,stream>>>(tattr, nullptr, edge_w, edge_b, tea, NT);

  for (int l = 0; l < 2; l++) {
    // GINEConv aggregation (fused message GEMM + in-block segment sum)
    hipMemsetAsync(buf1, 0, (size_t)NN * 66 * sizeof(float), stream);
    msg_aggr<<<gE,256,0,stream>>>(rowptr, srcS, dstS, permS, eattr,
                                  edge_w, edge_b, h, buf1);
    // node MLP: mid = relu((h+aggr)@w1+b1); z = mid@w2+b2
    rowgemm<66,66,0,1><<<gN,256,0,stream>>>(h,    buf1,    cw1 + l*66*66, cb1 + l*66, buf2, NN);
    rowgemm<66,66,0,0><<<gN,256,0,stream>>>(buf2, nullptr, cw2 + l*66*66, cb2 + l*66, buf1, NN);
    // batchnorm + h update
    hipMemsetAsync(stat, 0, 132 * sizeof(float), stream);
    bn_stats<<<(NN+1023)/1024,256,0,stream>>>(buf1, stat);
    bn_update<<<(NN*66+255)/256,256,0,stream>>>(h, buf1, stat, bng + l*66, bnb + l*66);
    // edge update: P1=h@W1a, P2=h@W1b per node; fused tile kernel does the rest
    const float* w1l = ew1 + (size_t)l*3*66*66;
    rowgemm<66,66,0,0><<<gN,256,0,stream>>>(h, nullptr, w1l,         nullptr, buf1, NN);
    rowgemm<66,66,0,0><<<gN,256,0,stream>>>(h, nullptr, w1l + 66*66, nullptr, buf2, NN);
    edge_fused<<<gT,256,0,stream>>>(buf1, buf2, eli, w1l + 2*66*66, eb1 + l*66,
                                    ew2 + (size_t)l*66*66, eb2 + l*66, tea);
  }

  // ---- final classifier ----
  rowgemm<66,50,1,0><<<gN,256,0,stream>>>(h, nullptr, mw1,         nullptr, buf1, NN);
  rowgemm<66,50,1,0><<<gN,256,0,stream>>>(h, nullptr, mw1 + 66*50, nullptr, buf2, NN);
  final_fused<<<gT,256,0,stream>>>(tea, buf1, buf2, eli, mw1 + 132*50, mb1,
                                   mw2, mb2, mw3, mb3, out);
}

// Round 4
// 1568.514 us; speedup vs baseline: 2.5844x; 1.2128x over previous
//
#include <hip/hip_runtime.h>

#define NN 100000   // nodes
#define NE 1000000  // edges (divisible by 64)
#define NT 200000   // target edges (divisible by 64)

typedef __attribute__((ext_vector_type(8))) short short8;
typedef __attribute__((ext_vector_type(4))) float f32x4;

__device__ __forceinline__ unsigned short f2b(float x) {  // fp32 -> bf16 RNE
  union { float f; unsigned int u; } v; v.f = x;
  unsigned int r = v.u + 0x7fffu + ((v.u >> 16) & 1u);
  return (unsigned short)(r >> 16);
}

// ---------------------------------------------------------------------------
// Weight prep: W[K][C] fp32 -> Wt[80][104] bf16 (transposed, zero-padded).
// Row n = output channel, col k = input channel; K padded to 96, C to 80.
// ---------------------------------------------------------------------------
struct WTab { const float* src[17]; int K[17]; int C[17]; };

__global__ __launch_bounds__(256) void prep_w(WTab tab, unsigned short* wT) {
  int b = blockIdx.x;
  const float* src = tab.src[b];
  int K = tab.K[b], C = tab.C[b];
  unsigned short* dst = wT + (size_t)b * 8320;
  for (int i = threadIdx.x; i < 8320; i += 256) {
    int c = i / 104, k = i - c * 104;
    float v = (c < C && k < K) ? src[k * C + c] : 0.0f;
    dst[i] = f2b(v);
  }
}

// ---------------------------------------------------------------------------
// Generic MFMA row-GEMM: out[R,C] = act(in (+add)) @ W + bias
// Block: 64 rows, 4 waves; wave w owns 16-row strip, CT col-tiles of 16.
// AIN: 0=f32, 1=f32+add, 2=relu(f32), 3=bf16 input. ROUT bit0=relu, bit1=bf16 out.
// ---------------------------------------------------------------------------
template<int K, int KSTEPS, int CT, int C, int AIN, int ROUT>
__global__ __launch_bounds__(256) void mfma_gemm(
    const void* __restrict__ in, const float* __restrict__ add,
    const unsigned short* __restrict__ Bt, const float* __restrict__ bias,
    void* __restrict__ outp, int R)
{
  __shared__ __align__(16) unsigned short As[64 * 104];
  __shared__ __align__(16) unsigned short Bs[80 * 104];
  __shared__ float bs[80];
  const int t = threadIdx.x;
  const int r0 = blockIdx.x * 64;
  for (int i = t; i < 1040; i += 256) ((uint4*)Bs)[i] = ((const uint4*)Bt)[i];
  if (t < 80) bs[t] = (bias && t < C) ? bias[t] : 0.0f;
  constexpr int KH = KSTEPS * 16;  // float2 slots per row
  for (int i = t; i < 64 * KH; i += 256) {
    int r = i / KH, kk = (i - r * KH) * 2;
    int rg = r0 + r;
    unsigned short u0 = 0, u1 = 0;
    if (rg < R && kk < K) {
      if constexpr (AIN == 3) {
        unsigned int u = ((const unsigned int*)in)[((size_t)rg * K + kk) >> 1];
        u0 = u & 0xffffu; u1 = u >> 16;
      } else {
        float2 f = *(const float2*)((const float*)in + (size_t)rg * K + kk);
        float v0 = f.x, v1 = f.y;
        if constexpr (AIN == 1) {
          float2 g = *(const float2*)(add + (size_t)rg * K + kk);
          v0 += g.x; v1 += g.y;
        }
        if constexpr (AIN == 2) { v0 = fmaxf(v0, 0.f); v1 = fmaxf(v1, 0.f); }
        u0 = f2b(v0); u1 = f2b(v1);
      }
    }
    As[r * 104 + kk] = u0; As[r * 104 + kk + 1] = u1;
  }
  __syncthreads();
  const int lane = t & 63, w = t >> 6, m = lane & 15, q = lane >> 4;
  f32x4 acc[CT] = {};
  const unsigned short* Ap = As + (w * 16 + m) * 104 + q * 8;
  const unsigned short* Bp = Bs + m * 104 + q * 8;
#pragma unroll
  for (int ks = 0; ks < KSTEPS; ks++) {
    short8 a = *(const short8*)(Ap + ks * 32);
#pragma unroll
    for (int ct = 0; ct < CT; ct++) {
      short8 b = *(const short8*)(Bp + ct * 16 * 104 + ks * 32);
      acc[ct] = __builtin_amdgcn_mfma_f32_16x16x32_bf16(a, b, acc[ct], 0, 0, 0);
    }
  }
#pragma unroll
  for (int ct = 0; ct < CT; ct++) {
    int c = ct * 16 + m;
    if (c < C) {
      float bv = bs[c];
#pragma unroll
      for (int r2 = 0; r2 < 4; r2++) {
        int row = r0 + w * 16 + q * 4 + r2;
        if (row < R) {
          float v = acc[ct][r2] + bv;
          if constexpr ((ROUT & 1) != 0) v = fmaxf(v, 0.f);
          if constexpr ((ROUT & 2) != 0)
            ((unsigned short*)outp)[(size_t)row * C + c] = f2b(v);
          else
            ((float*)outp)[(size_t)row * C + c] = v;
        }
      }
    }
  }
}

// ---------------------------------------------------------------------------
// CSR build
// ---------------------------------------------------------------------------
__global__ __launch_bounds__(256) void hist_kernel(const int* __restrict__ ei,
                                                   int* __restrict__ deg)
{
  int e = blockIdx.x * 256 + threadIdx.x;
  if (e < NE) atomicAdd(&deg[ei[NE + e]], 1);
}

__global__ __launch_bounds__(1024) void scan_kernel(const int* __restrict__ deg,
                                                    int* __restrict__ rowptr)
{
  __shared__ int sums[1024];
  const int t = threadIdx.x;
  const int CH = (NN + 1023) / 1024;
  int lo = t * CH, hi = lo + CH;
  if (hi > NN) hi = NN;
  int s = 0;
  for (int i = lo; i < hi; i++) s += deg[i];
  sums[t] = s;
  __syncthreads();
  for (int off = 1; off < 1024; off <<= 1) {
    int v = (t >= off) ? sums[t - off] : 0;
    __syncthreads();
    sums[t] += v;
    __syncthreads();
  }
  int run = (t == 0) ? 0 : sums[t - 1];
  for (int i = lo; i < hi; i++) { rowptr[i] = run; run += deg[i]; }
  if (t == 1023) rowptr[NN] = run;
}

__global__ __launch_bounds__(256) void fill_kernel(
    const int* __restrict__ ei, const int* __restrict__ rowptr,
    int* __restrict__ cur, int* __restrict__ srcS, int* __restrict__ dstS,
    int* __restrict__ permS)
{
  int e = blockIdx.x * 256 + threadIdx.x;
  if (e >= NE) return;
  int d = ei[NE + e];
  int pos = atomicAdd(&cur[d], 1);
  int w = rowptr[d] + pos;
  srcS[w] = ei[e];
  dstS[w] = d;
  permS[w] = e;
}

// Permute edge_attr into dst-sorted bf16 layout (write coalesced, once).
__global__ __launch_bounds__(256) void perm_eattr(
    const float* __restrict__ eattr, const int* __restrict__ permS,
    unsigned short* __restrict__ eaB)
{
  int i = blockIdx.x * 256 + threadIdx.x;
  if (i >= NE * 32) return;
  int w = i >> 5, k = i & 31;
  eaB[i] = f2b(eattr[(size_t)permS[w] * 32 + k]);
}

// ---------------------------------------------------------------------------
// GINE message + aggregation (dst-sorted, block = 64 edges).
// MFMA: msg = eattr_row @ edge_w; epilogue adds bias + h[src], relu -> LDS;
// then 66-thread segment sum over contiguous dst runs (boundary atomics).
// ---------------------------------------------------------------------------
__global__ __launch_bounds__(256) void msg_aggr2(
    const int* __restrict__ rowptr, const int* __restrict__ srcS,
    const int* __restrict__ dstS, const unsigned short* __restrict__ eaB,
    const float* __restrict__ eattr, const int* __restrict__ permS,
    const unsigned short* __restrict__ Bt, const float* __restrict__ bias,
    const float* __restrict__ h, float* __restrict__ aggr)
{
  __shared__ __align__(16) unsigned short As[64 * 40];
  __shared__ __align__(16) unsigned short Bs[80 * 104];
  __shared__ float msgS[64 * 67];
  __shared__ float bs[80];
  __shared__ int sidx[64], didx[64];
  const int t = threadIdx.x;
  const int e0 = blockIdx.x * 64;
  for (int i = t; i < 1040; i += 256) ((uint4*)Bs)[i] = ((const uint4*)Bt)[i];
  if (t < 80) bs[t] = (t < 66) ? bias[t] : 0.0f;
  if (t < 64) { sidx[t] = srcS[e0 + t]; didx[t] = dstS[e0 + t]; }
  if (eaB) {
    for (int i = t; i < 1024; i += 256) {
      int r = i >> 4, j = i & 15;
      unsigned int u = ((const unsigned int*)eaB)[(size_t)(e0 + r) * 16 + j];
      As[r * 40 + j * 2] = u & 0xffffu;
      As[r * 40 + j * 2 + 1] = u >> 16;
    }
  } else {
    for (int i = t; i < 1024; i += 256) {
      int r = i >> 4, j = i & 15;
      int p = permS[e0 + r];
      float2 f = ((const float2*)(eattr + (size_t)p * 32))[j];
      As[r * 40 + j * 2] = f2b(f.x);
      As[r * 40 + j * 2 + 1] = f2b(f.y);
    }
  }
  __syncthreads();
  const int lane = t & 63, w = t >> 6, m = lane & 15, q = lane >> 4;
  f32x4 acc[5] = {};
  short8 a = *(const short8*)(As + (w * 16 + m) * 40 + q * 8);
#pragma unroll
  for (int ct = 0; ct < 5; ct++) {
    short8 b = *(const short8*)(Bs + (ct * 16 + m) * 104 + q * 8);
    acc[ct] = __builtin_amdgcn_mfma_f32_16x16x32_bf16(a, b, acc[ct], 0, 0, 0);
  }
#pragma unroll
  for (int ct = 0; ct < 5; ct++) {
    int c = ct * 16 + m;
    if (c < 66) {
      float bv = bs[c];
#pragma unroll
      for (int r2 = 0; r2 < 4; r2++) {
        int e = w * 16 + q * 4 + r2;
        float v = acc[ct][r2] + bv + h[(size_t)sidx[e] * 66 + c];
        msgS[e * 67 + c] = fmaxf(v, 0.f);
      }
    }
  }
  __syncthreads();
  if (t < 66) {
    const int nfirst = didx[0], nlast = didx[63];
    const bool fp = rowptr[nfirst] < e0;
    const bool lp = rowptr[nlast + 1] > e0 + 64;
    float s = 0.0f;
    for (int e = 0; e < 64; e++) {
      s += msgS[e * 67 + t];
      bool bound = (e == 63) || (didx[e + 1] != didx[e]);
      if (bound) {
        int n = didx[e];
        if ((n == nfirst && fp) || (n == nlast && lp))
          atomicAdd(&aggr[(size_t)n * 66 + t], s);
        else
          aggr[(size_t)n * 66 + t] = s;
        s = 0.0f;
      }
    }
  }
}

// ---------------------------------------------------------------------------
// BatchNorm stats + update (fp32)
// ---------------------------------------------------------------------------
__global__ __launch_bounds__(256) void bn_stats(const float* __restrict__ z,
                                                float* __restrict__ stat)
{
  const int t = threadIdx.x;
  if (t >= 198) return;
  const int c = t % 66, rs = t / 66;
  const int r0 = blockIdx.x * 1024;
  float s1 = 0.0f, s2 = 0.0f;
  int rend = r0 + 1024; if (rend > NN) rend = NN;
  for (int r = r0 + rs; r < rend; r += 3) {
    float v = z[(size_t)r * 66 + c];
    s1 += v; s2 += v * v;
  }
  atomicAdd(&stat[c], s1);
  atomicAdd(&stat[66 + c], s2);
}

__global__ __launch_bounds__(256) void bn_update(
    float* __restrict__ h, const float* __restrict__ z,
    const float* __restrict__ stat,
    const float* __restrict__ gamma, const float* __restrict__ beta)
{
  int idx = blockIdx.x * 256 + threadIdx.x;
  if (idx >= NN * 66) return;
  int c = idx % 66;
  float mean = stat[c] * (1.0f / NN);
  float var  = stat[66 + c] * (1.0f / NN) - mean * mean;
  float inv  = rsqrtf(var + 1e-5f);
  float zn   = (z[idx] - mean) * inv * gamma[c] + beta[c];
  h[idx] = 0.5f * (h[idx] + fmaxf(zn, 0.0f));
}

// ---------------------------------------------------------------------------
// Fused edge update (block = 64 target edges), MFMA chain:
//   mid = relu(tea@W1c + b1 + P1[ts] + P2[td]);  tea += 0.5*(mid@W2 + b2)
// ---------------------------------------------------------------------------
__global__ __launch_bounds__(256) void edge_fused2(
    const float* __restrict__ P1, const float* __restrict__ P2,
    const int* __restrict__ eli, const unsigned short* __restrict__ B1t,
    const float* __restrict__ b1, const unsigned short* __restrict__ B2t,
    const float* __restrict__ b2, float* __restrict__ tea)
{
  __shared__ __align__(16) unsigned short As[64 * 104];  // tea tile, then mid
  __shared__ __align__(16) unsigned short Bs1[80 * 104];
  __shared__ __align__(16) unsigned short Bs2[80 * 104];
  __shared__ float b1s[80], b2s[80];
  __shared__ int sidx[64], didx[64];
  const int t = threadIdx.x;
  const int e0 = blockIdx.x * 64;
  for (int i = t; i < 1040; i += 256) {
    ((uint4*)Bs1)[i] = ((const uint4*)B1t)[i];
    ((uint4*)Bs2)[i] = ((const uint4*)B2t)[i];
  }
  if (t < 80) { b1s[t] = (t < 66) ? b1[t] : 0.f; b2s[t] = (t < 66) ? b2[t] : 0.f; }
  if (t < 64) { sidx[t] = eli[e0 + t]; didx[t] = eli[NT + e0 + t]; }
  for (int i = t; i < 64 * 48; i += 256) {  // stage tea: K=66 -> pad 96
    int r = i / 48, kk = (i - r * 48) * 2;
    unsigned short u0 = 0, u1 = 0;
    if (kk < 66) {
      float2 f = *(const float2*)(tea + (size_t)(e0 + r) * 66 + kk);
      u0 = f2b(f.x); u1 = f2b(f.y);
    }
    As[r * 104 + kk] = u0; As[r * 104 + kk + 1] = u1;
  }
  __syncthreads();
  const int lane = t & 63, w = t >> 6, m = lane & 15, q = lane >> 4;
  const unsigned short* Ap = As + (w * 16 + m) * 104 + q * 8;
  const unsigned short* Bp1 = Bs1 + m * 104 + q * 8;
  f32x4 acc[5] = {};
#pragma unroll
  for (int ks = 0; ks < 3; ks++) {
    short8 a = *(const short8*)(Ap + ks * 32);
#pragma unroll
    for (int ct = 0; ct < 5; ct++) {
      short8 b = *(const short8*)(Bp1 + ct * 16 * 104 + ks * 32);
      acc[ct] = __builtin_amdgcn_mfma_f32_16x16x32_bf16(a, b, acc[ct], 0, 0, 0);
    }
  }
  __syncthreads();  // all GEMM1 reads of As done before mid overwrite
#pragma unroll
  for (int ct = 0; ct < 5; ct++) {
    int c = ct * 16 + m;
    if (c < 66) {
      float bv = b1s[c];
#pragma unroll
      for (int r2 = 0; r2 < 4; r2++) {
        int e = w * 16 + q * 4 + r2;
        float v = acc[ct][r2] + bv + P1[(size_t)sidx[e] * 66 + c]
                                   + P2[(size_t)didx[e] * 66 + c];
        As[e * 104 + c] = f2b(fmaxf(v, 0.f));
      }
    }
  }
  __syncthreads();
  const unsigned short* Bp2 = Bs2 + m * 104 + q * 8;
  f32x4 acc2[5] = {};
#pragma unroll
  for (int ks = 0; ks < 3; ks++) {
    short8 a = *(const short8*)(Ap + ks * 32);
#pragma unroll
    for (int ct = 0; ct < 5; ct++) {
      short8 b = *(const short8*)(Bp2 + ct * 16 * 104 + ks * 32);
      acc2[ct] = __builtin_amdgcn_mfma_f32_16x16x32_bf16(a, b, acc2[ct], 0, 0, 0);
    }
  }
#pragma unroll
  for (int ct = 0; ct < 5; ct++) {
    int c = ct * 16 + m;
    if (c < 66) {
      float bv = b2s[c];
#pragma unroll
      for (int r2 = 0; r2 < 4; r2++) {
        int e = w * 16 + q * 4 + r2;
        size_t idx = (size_t)(e0 + e) * 66 + c;
        tea[idx] += 0.5f * (acc2[ct][r2] + bv);
      }
    }
  }
}

// ---------------------------------------------------------------------------
// Fused final classifier (block = 64 target edges):
//   o1 = relu(tea@mw1c + b1 + P1f[ts] + P2f[td]); o2 = relu(o1@w2+b2); out=o2@w3+b3
// ---------------------------------------------------------------------------
__global__ __launch_bounds__(256) void final_fused2(
    const float* __restrict__ tea, const float* __restrict__ P1f,
    const float* __restrict__ P2f, const int* __restrict__ eli,
    const unsigned short* __restrict__ B1t, const float* __restrict__ b1,
    const float* __restrict__ w2, const float* __restrict__ b2,
    const float* __restrict__ w3, const float* __restrict__ b3,
    float* __restrict__ out)
{
  __shared__ __align__(16) unsigned short As[64 * 104];
  __shared__ __align__(16) unsigned short Bs[64 * 104];
  __shared__ float o1s[64 * 51];
  __shared__ float o2s[64 * 25];
  __shared__ float w2s[50 * 25], w3s[50];
  __shared__ float b1s[64], b2s[25], b3s[2];
  __shared__ int sidx[64], didx[64];
  const int t = threadIdx.x;
  const int e0 = blockIdx.x * 64;
  for (int i = t; i < 832; i += 256) ((uint4*)Bs)[i] = ((const uint4*)B1t)[i];
  for (int i = t; i < 50 * 25; i += 256) w2s[i] = w2[i];
  if (t < 50) { w3s[t] = w3[t]; }
  if (t < 64) { b1s[t] = (t < 50) ? b1[t] : 0.f; sidx[t] = eli[e0 + t]; didx[t] = eli[NT + e0 + t]; }
  if (t < 25) b2s[t] = b2[t];
  if (t < 2)  b3s[t] = b3[t];
  for (int i = t; i < 64 * 48; i += 256) {
    int r = i / 48, kk = (i - r * 48) * 2;
    unsigned short u0 = 0, u1 = 0;
    if (kk < 66) {
      float2 f = *(const float2*)(tea + (size_t)(e0 + r) * 66 + kk);
      u0 = f2b(f.x); u1 = f2b(f.y);
    }
    As[r * 104 + kk] = u0; As[r * 104 + kk + 1] = u1;
  }
  __syncthreads();
  const int lane = t & 63, w = t >> 6, m = lane & 15, q = lane >> 4;
  const unsigned short* Ap = As + (w * 16 + m) * 104 + q * 8;
  const unsigned short* Bp = Bs + m * 104 + q * 8;
  f32x4 acc[4] = {};
#pragma unroll
  for (int ks = 0; ks < 3; ks++) {
    short8 a = *(const short8*)(Ap + ks * 32);
#pragma unroll
    for (int ct = 0; ct < 4; ct++) {
      short8 b = *(const short8*)(Bp + ct * 16 * 104 + ks * 32);
      acc[ct] = __builtin_amdgcn_mfma_f32_16x16x32_bf16(a, b, acc[ct], 0, 0, 0);
    }
  }
#pragma unroll
  for (int ct = 0; ct < 4; ct++) {
    int c = ct * 16 + m;
    if (c < 50) {
      float bv = b1s[c];
#pragma unroll
      for (int r2 = 0; r2 < 4; r2++) {
        int e = w * 16 + q * 4 + r2;
        float v = acc[ct][r2] + bv + P1f[(size_t)sidx[e] * 50 + c]
                                   + P2f[(size_t)didx[e] * 50 + c];
        o1s[e * 51 + c] = fmaxf(v, 0.f);
      }
    }
  }
  __syncthreads();
  for (int it = t; it < 64 * 25; it += 256) {
    int e = it / 25, c = it - e * 25;
    float s = b2s[c];
    for (int k = 0; k < 50; k++) s = fmaf(o1s[e * 51 + k], w2s[k * 25 + c], s);
    o2s[e * 25 + c] = fmaxf(s, 0.f);
  }
  __syncthreads();
  if (t < 128) {
    int e = t >> 1, c = t & 1;
    float s = b3s[c];
    for (int k = 0; k < 25; k++) s = fmaf(o2s[e * 25 + k], w3s[k * 2 + c], s);
    out[(size_t)(e0 + e) * 2 + c] = s;
  }
}

// ---------------------------------------------------------------------------
extern "C" void kernel_launch(void* const* d_in, const int* in_sizes, int n_in,
                              void* d_out, int out_size, void* d_ws, size_t ws_size,
                              hipStream_t stream) {
  const float* x      = (const float*)d_in[0];
  const int*   ei     = (const int*)  d_in[1];
  const float* eattr  = (const float*)d_in[2];
  const int*   eli    = (const int*)  d_in[3];
  const float* tattr  = (const float*)d_in[4];
  const float* node_w = (const float*)d_in[5];
  const float* node_b = (const float*)d_in[6];
  const float* edge_w = (const float*)d_in[7];
  const float* edge_b = (const float*)d_in[8];
  const float* cw1    = (const float*)d_in[9];
  const float* cb1    = (const float*)d_in[10];
  const float* cw2    = (const float*)d_in[11];
  const float* cb2    = (const float*)d_in[12];
  const float* bng    = (const float*)d_in[13];
  const float* bnb    = (const float*)d_in[14];
  const float* ew1    = (const float*)d_in[15];
  const float* eb1    = (const float*)d_in[16];
  const float* ew2    = (const float*)d_in[17];
  const float* eb2    = (const float*)d_in[18];
  const float* mw1    = (const float*)d_in[19];
  const float* mb1    = (const float*)d_in[20];
  const float* mw2    = (const float*)d_in[21];
  const float* mb2    = (const float*)d_in[22];
  const float* mw3    = (const float*)d_in[23];
  const float* mb3    = (const float*)d_in[24];
  float* out = (float*)d_out;

  // ---- workspace layout ----
  char* p = (char*)d_ws;
  auto alloc = [&](size_t bytes) { void* r = p; p += (bytes + 255) & ~(size_t)255; return r; };
  float* h      = (float*)alloc((size_t)NN * 66 * 4);
  float* buf1   = (float*)alloc((size_t)NN * 66 * 4);
  float* buf2   = (float*)alloc((size_t)NN * 66 * 4);  // also hosts midb (bf16)
  float* tea    = (float*)alloc((size_t)NT * 66 * 4);
  float* stat   = (float*)alloc(1024);
  int*   rowptr = (int*)alloc((NN + 1) * 4);
  int*   cur    = (int*)alloc((size_t)NN * 4);
  int*   srcS   = (int*)alloc((size_t)NE * 4);
  int*   dstS   = (int*)alloc((size_t)NE * 4);
  int*   permS  = (int*)alloc((size_t)NE * 4);
  unsigned short* wT = (unsigned short*)alloc((size_t)17 * 8320 * 2);
  size_t used = (size_t)(p - (char*)d_ws);
  unsigned short* eaB = nullptr;
  if (ws_size >= used + (size_t)NE * 32 * 2 + 256)
    eaB = (unsigned short*)alloc((size_t)NE * 32 * 2);

  const int gN = (NN + 63) / 64;  // 1563
  const int gT = NT / 64;         // 3125
  const int gE = NE / 64;         // 15625
  auto slot = [&](int i) { return wT + (size_t)i * 8320; };

  // ---- CSR build ----
  hipMemsetAsync(cur, 0, (size_t)NN * sizeof(int), stream);
  hist_kernel<<<(NE + 255) / 256, 256, 0, stream>>>(ei, cur);
  scan_kernel<<<1, 1024, 0, stream>>>(cur, rowptr);
  hipMemsetAsync(cur, 0, (size_t)NN * sizeof(int), stream);
  fill_kernel<<<(NE + 255) / 256, 256, 0, stream>>>(ei, rowptr, cur, srcS, dstS, permS);
  if (eaB)
    perm_eattr<<<(NE * 32) / 256, 256, 0, stream>>>(eattr, permS, eaB);

  // ---- weight prep: 17 matrices -> bf16 transposed [80][104] ----
  WTab tab;
  tab.src[0] = node_w; tab.K[0] = 64; tab.C[0] = 66;
  tab.src[1] = edge_w; tab.K[1] = 32; tab.C[1] = 66;
  for (int l = 0; l < 2; l++) {
    tab.src[2 + l] = cw1 + (size_t)l * 4356; tab.K[2 + l] = 66; tab.C[2 + l] = 66;
    tab.src[4 + l] = cw2 + (size_t)l * 4356; tab.K[4 + l] = 66; tab.C[4 + l] = 66;
    for (int j = 0; j < 3; j++) {
      tab.src[6 + 3 * l + j] = ew1 + (size_t)l * 13068 + (size_t)j * 4356;
      tab.K[6 + 3 * l + j] = 66; tab.C[6 + 3 * l + j] = 66;
    }
    tab.src[12 + l] = ew2 + (size_t)l * 4356; tab.K[12 + l] = 66; tab.C[12 + l] = 66;
  }
  for (int j = 0; j < 3; j++) {
    tab.src[14 + j] = mw1 + (size_t)j * 3300; tab.K[14 + j] = 66; tab.C[14 + j] = 50;
  }
  prep_w<<<17, 256, 0, stream>>>(tab, wT);

  // ---- embeds ----
  mfma_gemm<64, 2, 5, 66, 0, 0><<<gN, 256, 0, stream>>>(x, nullptr, slot(0), node_b, h, NN);
  mfma_gemm<32, 1, 5, 66, 0, 0><<<gT, 256, 0, stream>>>(tattr, nullptr, slot(1), edge_b, tea, NT);

  for (int l = 0; l < 2; l++) {
    // aggregation
    hipMemsetAsync(buf1, 0, (size_t)NN * 66 * sizeof(float), stream);
    msg_aggr2<<<gE, 256, 0, stream>>>(rowptr, srcS, dstS, eaB, eattr, permS,
                                      slot(1), edge_b, h, buf1);
    // node MLP: midb = bf16(relu((h+aggr)@cw1+b1)); z = midb@cw2+b2
    mfma_gemm<66, 3, 5, 66, 1, 3><<<gN, 256, 0, stream>>>(
        h, buf1, slot(2 + l), cb1 + l * 66, (unsigned short*)buf2, NN);
    mfma_gemm<66, 3, 5, 66, 3, 0><<<gN, 256, 0, stream>>>(
        (unsigned short*)buf2, nullptr, slot(4 + l), cb2 + l * 66, buf1, NN);
    // batchnorm + h update
    hipMemsetAsync(stat, 0, 132 * sizeof(float), stream);
    bn_stats<<<(NN + 1023) / 1024, 256, 0, stream>>>(buf1, stat);
    bn_update<<<(NN * 66 + 255) / 256, 256, 0, stream>>>(h, buf1, stat,
                                                         bng + l * 66, bnb + l * 66);
    // edge update
    mfma_gemm<66, 3, 5, 66, 0, 0><<<gN, 256, 0, stream>>>(h, nullptr, slot(6 + 3 * l), nullptr, buf1, NN);
    mfma_gemm<66, 3, 5, 66, 0, 0><<<gN, 256, 0, stream>>>(h, nullptr, slot(7 + 3 * l), nullptr, buf2, NN);
    edge_fused2<<<gT, 256, 0, stream>>>(buf1, buf2, eli, slot(8 + 3 * l), eb1 + l * 66,
                                        slot(12 + l), eb2 + l * 66, tea);
  }

  // ---- final classifier ----
  mfma_gemm<66, 3, 4, 50, 2, 0><<<gN, 256, 0, stream>>>(h, nullptr, slot(14), nullptr, buf1, NN);
  mfma_gemm<66, 3, 4, 50, 2, 0><<<gN, 256, 0, stream>>>(h, nullptr, slot(15), nullptr, buf2, NN);
  final_fused2<<<gT, 256, 0, stream>>>(tea, buf1, buf2, eli, slot(16), mb1,
                                       mw2, mb2, mw3, mb3, out);
}

// Round 5
// 1284.315 us; speedup vs baseline: 3.1563x; 1.2213x over previous
//
#include <hip/hip_runtime.h>

#define NN 100000   // nodes
#define NE 1000000  // edges (divisible by 64)
#define NT 200000   // target edges (divisible by 64)
#define SCB 391     // ceil(NN/256) scan blocks

typedef __attribute__((ext_vector_type(8))) short short8;
typedef __attribute__((ext_vector_type(4))) float f32x4;

__device__ __forceinline__ unsigned short f2b(float x) {  // fp32 -> bf16 RNE
  union { float f; unsigned int u; } v; v.f = x;
  unsigned int r = v.u + 0x7fffu + ((v.u >> 16) & 1u);
  return (unsigned short)(r >> 16);
}
__device__ __forceinline__ float b2f(unsigned short x) {
  union { unsigned int u; float f; } v; v.u = ((unsigned int)x) << 16;
  return v.f;
}

// ---------------------------------------------------------------------------
// Weight prep: up to two fp32 sources [K][C] -> bf16 transposed tile
// [rows][104]; row c<C from A col c, C<=c<2C from B col c-C, rest zero.
// ---------------------------------------------------------------------------
struct PrepTab {
  const float* a[14]; const float* b[14];
  int K[14], C[14], rows[14], off[14];
};

__global__ __launch_bounds__(256) void prep_w(PrepTab tab, unsigned short* wT) {
  int s = blockIdx.x;
  const float* A = tab.a[s];
  const float* B = tab.b[s];
  int K = tab.K[s], C = tab.C[s], rows = tab.rows[s];
  unsigned short* dst = wT + tab.off[s];
  int n = rows * 104;
  for (int i = threadIdx.x; i < n; i += 256) {
    int c = i / 104, k = i - c * 104;
    float v = 0.0f;
    if (k < K) {
      if (c < C) v = A[k * C + c];
      else if (B && c < 2 * C) v = B[k * C + (c - C)];
    }
    dst[i] = f2b(v);
  }
}

// ---------------------------------------------------------------------------
// Generic MFMA row-GEMM: out[R,C] = act(in (+add)) @ W + bias
// AIN: 0=f32, 1=f32+add, 2=relu(f32), 3=bf16 input.
// ROUT bit0=relu, bit1=bf16 out, bit2=also write bf16 mirror to out2.
// ---------------------------------------------------------------------------
template<int K, int KSTEPS, int CT, int C, int AIN, int ROUT>
__global__ __launch_bounds__(256) void mfma_gemm(
    const void* __restrict__ in, const float* __restrict__ add,
    const unsigned short* __restrict__ Bt, const float* __restrict__ bias,
    void* __restrict__ outp, void* __restrict__ out2, int R)
{
  constexpr int CR = CT * 16;
  __shared__ __align__(16) unsigned short As[64 * 104];
  __shared__ __align__(16) unsigned short Bs[CR * 104];
  __shared__ float bs[CR];
  const int t = threadIdx.x;
  const int r0 = blockIdx.x * 64;
  for (int i = t; i < CT * 208; i += 256) ((uint4*)Bs)[i] = ((const uint4*)Bt)[i];
  if (t < CR) bs[t] = (bias && t < C) ? bias[t] : 0.0f;
  constexpr int KH = KSTEPS * 16;  // float2 slots per row
  for (int i = t; i < 64 * KH; i += 256) {
    int r = i / KH, kk = (i - r * KH) * 2;
    int rg = r0 + r;
    unsigned short u0 = 0, u1 = 0;
    if (rg < R && kk < K) {
      if constexpr (AIN == 3) {
        unsigned int u = ((const unsigned int*)in)[((size_t)rg * K + kk) >> 1];
        u0 = u & 0xffffu; u1 = u >> 16;
      } else {
        float2 f = *(const float2*)((const float*)in + (size_t)rg * K + kk);
        float v0 = f.x, v1 = f.y;
        if constexpr (AIN == 1) {
          float2 g = *(const float2*)(add + (size_t)rg * K + kk);
          v0 += g.x; v1 += g.y;
        }
        if constexpr (AIN == 2) { v0 = fmaxf(v0, 0.f); v1 = fmaxf(v1, 0.f); }
        u0 = f2b(v0); u1 = f2b(v1);
      }
    }
    As[r * 104 + kk] = u0; As[r * 104 + kk + 1] = u1;
  }
  __syncthreads();
  const int lane = t & 63, w = t >> 6, m = lane & 15, q = lane >> 4;
  f32x4 acc[CT] = {};
  const unsigned short* Ap = As + (w * 16 + m) * 104 + q * 8;
  const unsigned short* Bp = Bs + m * 104 + q * 8;
#pragma unroll
  for (int ks = 0; ks < KSTEPS; ks++) {
    short8 a = *(const short8*)(Ap + ks * 32);
#pragma unroll
    for (int ct = 0; ct < CT; ct++) {
      short8 b = *(const short8*)(Bp + ct * 16 * 104 + ks * 32);
      acc[ct] = __builtin_amdgcn_mfma_f32_16x16x32_bf16(a, b, acc[ct], 0, 0, 0);
    }
  }
#pragma unroll
  for (int ct = 0; ct < CT; ct++) {
    int c = ct * 16 + m;
    if (c < C) {
      float bv = bs[c];
#pragma unroll
      for (int r2 = 0; r2 < 4; r2++) {
        int row = r0 + w * 16 + q * 4 + r2;
        if (row < R) {
          float v = acc[ct][r2] + bv;
          if constexpr ((ROUT & 1) != 0) v = fmaxf(v, 0.f);
          if constexpr ((ROUT & 2) != 0)
            ((unsigned short*)outp)[(size_t)row * C + c] = f2b(v);
          else
            ((float*)outp)[(size_t)row * C + c] = v;
          if constexpr ((ROUT & 4) != 0)
            ((unsigned short*)out2)[(size_t)row * C + c] = f2b(v);
        }
      }
    }
  }
}

// ---------------------------------------------------------------------------
// CSR build: histogram + 3-pass coalesced scan + fill
// ---------------------------------------------------------------------------
__global__ __launch_bounds__(256) void hist_kernel(const int* __restrict__ ei,
                                                   int* __restrict__ deg)
{
  int e = blockIdx.x * 256 + threadIdx.x;
  if (e < NE) atomicAdd(&deg[ei[NE + e]], 1);
}

__global__ __launch_bounds__(256) void blocksum_k(const int* __restrict__ deg,
                                                  int* __restrict__ bsum)
{
  __shared__ int red[256];
  const int t = threadIdx.x;
  int i = blockIdx.x * 256 + t;
  red[t] = (i < NN) ? deg[i] : 0;
  __syncthreads();
  for (int s = 128; s > 0; s >>= 1) {
    if (t < s) red[t] += red[t + s];
    __syncthreads();
  }
  if (t == 0) bsum[blockIdx.x] = red[0];
}

__global__ __launch_bounds__(512) void scansums_k(int* __restrict__ bsum,
                                                  int* __restrict__ rowptr)
{
  __shared__ int s[512];
  const int t = threadIdx.x;
  s[t] = (t < SCB) ? bsum[t] : 0;
  __syncthreads();
  for (int off = 1; off < 512; off <<= 1) {
    int v = (t >= off) ? s[t - off] : 0;
    __syncthreads();
    s[t] += v;
    __syncthreads();
  }
  if (t < SCB) bsum[t] = (t == 0) ? 0 : s[t - 1];  // exclusive
  if (t == 0) rowptr[NN] = NE;
}

__global__ __launch_bounds__(256) void scatter_scan_k(
    const int* __restrict__ deg, const int* __restrict__ bsum,
    int* __restrict__ rowptr)
{
  __shared__ int s[256];
  const int t = threadIdx.x;
  int i = blockIdx.x * 256 + t;
  int v = (i < NN) ? deg[i] : 0;
  s[t] = v;
  __syncthreads();
  for (int off = 1; off < 256; off <<= 1) {
    int x = (t >= off) ? s[t - off] : 0;
    __syncthreads();
    s[t] += x;
    __syncthreads();
  }
  if (i < NN) rowptr[i] = bsum[blockIdx.x] + s[t] - v;
}

__global__ __launch_bounds__(256) void fill_kernel(
    const int* __restrict__ ei, const int* __restrict__ rowptr,
    int* __restrict__ cur, int* __restrict__ srcS, int* __restrict__ dstS,
    int* __restrict__ permS, int* __restrict__ invp)
{
  int e = blockIdx.x * 256 + threadIdx.x;
  if (e >= NE) return;
  int d = ei[NE + e];
  int pos = atomicAdd(&cur[d], 1);
  int w = rowptr[d] + pos;
  srcS[w] = ei[e];
  dstS[w] = d;
  permS[w] = e;
  invp[e] = w;
}

// Linear-read, scatter-write permutation of edge_attr into dst-sorted bf16.
__global__ __launch_bounds__(256) void perm_eattr(
    const float* __restrict__ eattr, const int* __restrict__ invp,
    unsigned short* __restrict__ eaB)
{
  int i = blockIdx.x * 256 + threadIdx.x;  // over NE*16 float2 slots
  if (i >= NE * 16) return;
  int e = i >> 4, j = i & 15;
  float2 f = ((const float2*)eattr)[i];
  unsigned int packed = (unsigned int)f2b(f.x) | ((unsigned int)f2b(f.y) << 16);
  ((unsigned int*)eaB)[(size_t)invp[e] * 16 + j] = packed;
}

// ---------------------------------------------------------------------------
// GINE message + aggregation (dst-sorted, block = 64 edges).
// MFMA msg GEMM -> epilogue adds bias + hB[src] (bf16 mirror), relu -> LDS;
// run-parallel segmented sum (thread = run x channel), boundary atomics.
// ---------------------------------------------------------------------------
__global__ __launch_bounds__(256) void msg_aggr2(
    const int* __restrict__ rowptr, const int* __restrict__ srcS,
    const int* __restrict__ dstS, const unsigned short* __restrict__ eaB,
    const float* __restrict__ eattr, const int* __restrict__ permS,
    const unsigned short* __restrict__ Bt, const float* __restrict__ bias,
    const unsigned short* __restrict__ hB, float* __restrict__ aggr)
{
  __shared__ __align__(16) unsigned short As[64 * 40];
  __shared__ __align__(16) unsigned short Bs[80 * 104];
  __shared__ float msgS[64 * 67];
  __shared__ float bs[80];
  __shared__ int sidx[64], didx[64];
  __shared__ int runStart[65];
  __shared__ int nrunsS;
  const int t = threadIdx.x;
  const int e0 = blockIdx.x * 64;
  for (int i = t; i < 1040; i += 256) ((uint4*)Bs)[i] = ((const uint4*)Bt)[i];
  if (t < 80) bs[t] = (t < 66) ? bias[t] : 0.0f;
  if (t < 64) { sidx[t] = srcS[e0 + t]; didx[t] = dstS[e0 + t]; }
  if (eaB) {
    for (int i = t; i < 1024; i += 256) {
      int r = i >> 4, j = i & 15;
      unsigned int u = ((const unsigned int*)eaB)[(size_t)(e0 + r) * 16 + j];
      As[r * 40 + j * 2] = u & 0xffffu;
      As[r * 40 + j * 2 + 1] = u >> 16;
    }
  } else {
    for (int i = t; i < 1024; i += 256) {
      int r = i >> 4, j = i & 15;
      int p = permS[e0 + r];
      float2 f = ((const float2*)(eattr + (size_t)p * 32))[j];
      As[r * 40 + j * 2] = f2b(f.x);
      As[r * 40 + j * 2 + 1] = f2b(f.y);
    }
  }
  __syncthreads();
  // run boundary detection (wave 0 = threads 0..63)
  if (t < 64) {
    bool b = (t == 0) || (didx[t] != didx[t - 1]);
    unsigned long long mask = __ballot(b);
    int idx = __popcll(mask & ((1ull << t) - 1ull));
    if (b) runStart[idx] = t;
    if (t == 63) { nrunsS = __popcll(mask); runStart[__popcll(mask)] = 64; }
  }
  const int lane = t & 63, w = t >> 6, m = lane & 15, q = lane >> 4;
  f32x4 acc[5] = {};
  short8 a = *(const short8*)(As + (w * 16 + m) * 40 + q * 8);
#pragma unroll
  for (int ct = 0; ct < 5; ct++) {
    short8 b = *(const short8*)(Bs + (ct * 16 + m) * 104 + q * 8);
    acc[ct] = __builtin_amdgcn_mfma_f32_16x16x32_bf16(a, b, acc[ct], 0, 0, 0);
  }
#pragma unroll
  for (int ct = 0; ct < 5; ct++) {
    int c = ct * 16 + m;
    if (c < 66) {
      float bv = bs[c];
#pragma unroll
      for (int r2 = 0; r2 < 4; r2++) {
        int e = w * 16 + q * 4 + r2;
        float v = acc[ct][r2] + bv + b2f(hB[(size_t)sidx[e] * 66 + c]);
        msgS[e * 67 + c] = fmaxf(v, 0.f);
      }
    }
  }
  __syncthreads();
  const int nr = nrunsS;
  for (int task = t; task < nr * 66; task += 256) {
    int r = task / 66, c = task - r * 66;
    int s0 = runStart[r], s1 = runStart[r + 1];
    float s = 0.0f;
    for (int e = s0; e < s1; e++) s += msgS[e * 67 + c];
    int n = didx[s0];
    bool partial = false;
    if (r == 0)      partial = (rowptr[n] < e0);
    if (r == nr - 1) partial = partial || (rowptr[n + 1] > e0 + 64);
    if (partial) atomicAdd(&aggr[(size_t)n * 66 + c], s);
    else         aggr[(size_t)n * 66 + c] = s;
  }
}

// ---------------------------------------------------------------------------
// BatchNorm stats + update (fp32); bn_update also refreshes hB mirror.
// ---------------------------------------------------------------------------
__global__ __launch_bounds__(256) void bn_stats(const float* __restrict__ z,
                                                float* __restrict__ stat)
{
  const int t = threadIdx.x;
  if (t >= 198) return;
  const int c = t % 66, rs = t / 66;
  const int r0 = blockIdx.x * 1024;
  float s1 = 0.0f, s2 = 0.0f;
  int rend = r0 + 1024; if (rend > NN) rend = NN;
  for (int r = r0 + rs; r < rend; r += 3) {
    float v = z[(size_t)r * 66 + c];
    s1 += v; s2 += v * v;
  }
  atomicAdd(&stat[c], s1);
  atomicAdd(&stat[66 + c], s2);
}

__global__ __launch_bounds__(256) void bn_update(
    float* __restrict__ h, unsigned short* __restrict__ hB,
    const float* __restrict__ z, const float* __restrict__ stat,
    const float* __restrict__ gamma, const float* __restrict__ beta)
{
  int idx = blockIdx.x * 256 + threadIdx.x;
  if (idx >= NN * 66) return;
  int c = idx % 66;
  float mean = stat[c] * (1.0f / NN);
  float var  = stat[66 + c] * (1.0f / NN) - mean * mean;
  float inv  = rsqrtf(var + 1e-5f);
  float zn   = (z[idx] - mean) * inv * gamma[c] + beta[c];
  float v = 0.5f * (h[idx] + fmaxf(zn, 0.0f));
  h[idx] = v;
  hB[idx] = f2b(v);
}

// ---------------------------------------------------------------------------
// Fused edge update (block = 64 target edges), MFMA chain:
//   mid = relu(tea@W1c + b1 + P12[ts,0:66] + P12[td,66:132]);
//   tea += 0.5*(mid@W2 + b2)
// ---------------------------------------------------------------------------
__global__ __launch_bounds__(256) void edge_fused2(
    const float* __restrict__ P12, const int* __restrict__ eli,
    const unsigned short* __restrict__ B1t, const float* __restrict__ b1,
    const unsigned short* __restrict__ B2t, const float* __restrict__ b2,
    float* __restrict__ tea)
{
  __shared__ __align__(16) unsigned short As[64 * 104];  // tea tile, then mid
  __shared__ __align__(16) unsigned short Bs1[80 * 104];
  __shared__ __align__(16) unsigned short Bs2[80 * 104];
  __shared__ float b1s[80], b2s[80];
  __shared__ int sidx[64], didx[64];
  const int t = threadIdx.x;
  const int e0 = blockIdx.x * 64;
  for (int i = t; i < 1040; i += 256) {
    ((uint4*)Bs1)[i] = ((const uint4*)B1t)[i];
    ((uint4*)Bs2)[i] = ((const uint4*)B2t)[i];
  }
  if (t < 80) { b1s[t] = (t < 66) ? b1[t] : 0.f; b2s[t] = (t < 66) ? b2[t] : 0.f; }
  if (t < 64) { sidx[t] = eli[e0 + t]; didx[t] = eli[NT + e0 + t]; }
  for (int i = t; i < 64 * 48; i += 256) {
    int r = i / 48, kk = (i - r * 48) * 2;
    unsigned short u0 = 0, u1 = 0;
    if (kk < 66) {
      float2 f = *(const float2*)(tea + (size_t)(e0 + r) * 66 + kk);
      u0 = f2b(f.x); u1 = f2b(f.y);
    }
    As[r * 104 + kk] = u0; As[r * 104 + kk + 1] = u1;
  }
  __syncthreads();
  const int lane = t & 63, w = t >> 6, m = lane & 15, q = lane >> 4;
  const unsigned short* Ap = As + (w * 16 + m) * 104 + q * 8;
  const unsigned short* Bp1 = Bs1 + m * 104 + q * 8;
  f32x4 acc[5] = {};
#pragma unroll
  for (int ks = 0; ks < 3; ks++) {
    short8 a = *(const short8*)(Ap + ks * 32);
#pragma unroll
    for (int ct = 0; ct < 5; ct++) {
      short8 b = *(const short8*)(Bp1 + ct * 16 * 104 + ks * 32);
      acc[ct] = __builtin_amdgcn_mfma_f32_16x16x32_bf16(a, b, acc[ct], 0, 0, 0);
    }
  }
  __syncthreads();  // GEMM1 reads of As done before mid overwrite
#pragma unroll
  for (int ct = 0; ct < 5; ct++) {
    int c = ct * 16 + m;
    if (c < 66) {
      float bv = b1s[c];
#pragma unroll
      for (int r2 = 0; r2 < 4; r2++) {
        int e = w * 16 + q * 4 + r2;
        float v = acc[ct][r2] + bv + P12[(size_t)sidx[e] * 132 + c]
                                   + P12[(size_t)didx[e] * 132 + 66 + c];
        As[e * 104 + c] = f2b(fmaxf(v, 0.f));
      }
    }
  }
  __syncthreads();
  const unsigned short* Bp2 = Bs2 + m * 104 + q * 8;
  f32x4 acc2[5] = {};
#pragma unroll
  for (int ks = 0; ks < 3; ks++) {
    short8 a = *(const short8*)(Ap + ks * 32);
#pragma unroll
    for (int ct = 0; ct < 5; ct++) {
      short8 b = *(const short8*)(Bp2 + ct * 16 * 104 + ks * 32);
      acc2[ct] = __builtin_amdgcn_mfma_f32_16x16x32_bf16(a, b, acc2[ct], 0, 0, 0);
    }
  }
#pragma unroll
  for (int ct = 0; ct < 5; ct++) {
    int c = ct * 16 + m;
    if (c < 66) {
      float bv = b2s[c];
#pragma unroll
      for (int r2 = 0; r2 < 4; r2++) {
        int e = w * 16 + q * 4 + r2;
        size_t idx = (size_t)(e0 + e) * 66 + c;
        tea[idx] += 0.5f * (acc2[ct][r2] + bv);
      }
    }
  }
}

// ---------------------------------------------------------------------------
// Fused final classifier (block = 64 target edges):
//   o1 = relu(tea@mw1c + b1 + P12f[ts,0:50] + P12f[td,50:100]);
//   o2 = relu(o1@w2+b2); out = o2@w3+b3
// ---------------------------------------------------------------------------
__global__ __launch_bounds__(256) void final_fused2(
    const float* __restrict__ tea, const float* __restrict__ P12f,
    const int* __restrict__ eli, const unsigned short* __restrict__ B1t,
    const float* __restrict__ b1, const float* __restrict__ w2,
    const float* __restrict__ b2, const float* __restrict__ w3,
    const float* __restrict__ b3, float* __restrict__ out)
{
  __shared__ __align__(16) unsigned short As[64 * 104];
  __shared__ __align__(16) unsigned short Bs[64 * 104];
  __shared__ float o1s[64 * 51];
  __shared__ float o2s[64 * 25];
  __shared__ float w2s[50 * 25], w3s[50];
  __shared__ float b1s[64], b2s[25], b3s[2];
  __shared__ int sidx[64], didx[64];
  const int t = threadIdx.x;
  const int e0 = blockIdx.x * 64;
  for (int i = t; i < 832; i += 256) ((uint4*)Bs)[i] = ((const uint4*)B1t)[i];
  for (int i = t; i < 50 * 25; i += 256) w2s[i] = w2[i];
  if (t < 50) w3s[t] = w3[t];
  if (t < 64) { b1s[t] = (t < 50) ? b1[t] : 0.f; sidx[t] = eli[e0 + t]; didx[t] = eli[NT + e0 + t]; }
  if (t < 25) b2s[t] = b2[t];
  if (t < 2)  b3s[t] = b3[t];
  for (int i = t; i < 64 * 48; i += 256) {
    int r = i / 48, kk = (i - r * 48) * 2;
    unsigned short u0 = 0, u1 = 0;
    if (kk < 66) {
      float2 f = *(const float2*)(tea + (size_t)(e0 + r) * 66 + kk);
      u0 = f2b(f.x); u1 = f2b(f.y);
    }
    As[r * 104 + kk] = u0; As[r * 104 + kk + 1] = u1;
  }
  __syncthreads();
  const int lane = t & 63, w = t >> 6, m = lane & 15, q = lane >> 4;
  const unsigned short* Ap = As + (w * 16 + m) * 104 + q * 8;
  const unsigned short* Bp = Bs + m * 104 + q * 8;
  f32x4 acc[4] = {};
#pragma unroll
  for (int ks = 0; ks < 3; ks++) {
    short8 a = *(const short8*)(Ap + ks * 32);
#pragma unroll
    for (int ct = 0; ct < 4; ct++) {
      short8 b = *(const short8*)(Bp + ct * 16 * 104 + ks * 32);
      acc[ct] = __builtin_amdgcn_mfma_f32_16x16x32_bf16(a, b, acc[ct], 0, 0, 0);
    }
  }
#pragma unroll
  for (int ct = 0; ct < 4; ct++) {
    int c = ct * 16 + m;
    if (c < 50) {
      float bv = b1s[c];
#pragma unroll
      for (int r2 = 0; r2 < 4; r2++) {
        int e = w * 16 + q * 4 + r2;
        float v = acc[ct][r2] + bv + P12f[(size_t)sidx[e] * 100 + c]
                                   + P12f[(size_t)didx[e] * 100 + 50 + c];
        o1s[e * 51 + c] = fmaxf(v, 0.f);
      }
    }
  }
  __syncthreads();
  for (int it = t; it < 64 * 25; it += 256) {
    int e = it / 25, c = it - e * 25;
    float s = b2s[c];
    for (int k = 0; k < 50; k++) s = fmaf(o1s[e * 51 + k], w2s[k * 25 + c], s);
    o2s[e * 25 + c] = fmaxf(s, 0.f);
  }
  __syncthreads();
  if (t < 128) {
    int e = t >> 1, c = t & 1;
    float s = b3s[c];
    for (int k = 0; k < 25; k++) s = fmaf(o2s[e * 25 + k], w3s[k * 2 + c], s);
    out[(size_t)(e0 + e) * 2 + c] = s;
  }
}

// ---------------------------------------------------------------------------
extern "C" void kernel_launch(void* const* d_in, const int* in_sizes, int n_in,
                              void* d_out, int out_size, void* d_ws, size_t ws_size,
                              hipStream_t stream) {
  const float* x      = (const float*)d_in[0];
  const int*   ei     = (const int*)  d_in[1];
  const float* eattr  = (const float*)d_in[2];
  const int*   eli    = (const int*)  d_in[3];
  const float* tattr  = (const float*)d_in[4];
  const float* node_w = (const float*)d_in[5];
  const float* node_b = (const float*)d_in[6];
  const float* edge_w = (const float*)d_in[7];
  const float* edge_b = (const float*)d_in[8];
  const float* cw1    = (const float*)d_in[9];
  const float* cb1    = (const float*)d_in[10];
  const float* cw2    = (const float*)d_in[11];
  const float* cb2    = (const float*)d_in[12];
  const float* bng    = (const float*)d_in[13];
  const float* bnb    = (const float*)d_in[14];
  const float* ew1    = (const float*)d_in[15];
  const float* eb1    = (const float*)d_in[16];
  const float* ew2    = (const float*)d_in[17];
  const float* eb2    = (const float*)d_in[18];
  const float* mw1    = (const float*)d_in[19];
  const float* mb1    = (const float*)d_in[20];
  const float* mw2    = (const float*)d_in[21];
  const float* mb2    = (const float*)d_in[22];
  const float* mw3    = (const float*)d_in[23];
  const float* mb3    = (const float*)d_in[24];
  float* out = (float*)d_out;

  // ---- workspace layout (optional eaB last) ----
  char* p = (char*)d_ws;
  auto alloc = [&](size_t bytes) { void* r = p; p += (bytes + 255) & ~(size_t)255; return r; };
  float* h      = (float*)alloc((size_t)NN * 66 * 4);
  unsigned short* hB = (unsigned short*)alloc((size_t)NN * 66 * 2);
  float* big    = (float*)alloc((size_t)NN * 132 * 4);  // P12 / P12f / midb
  float* zbuf   = (float*)alloc((size_t)NN * 66 * 4);   // aggr / z
  float* tea    = (float*)alloc((size_t)NT * 66 * 4);
  float* stat   = (float*)alloc(1024);
  int*   rowptr = (int*)alloc((NN + 1) * 4);
  int*   cur    = (int*)alloc((size_t)NN * 4);
  int*   bsum   = (int*)alloc((SCB + 1) * 4);
  int*   srcS   = (int*)alloc((size_t)NE * 4);
  int*   dstS   = (int*)alloc((size_t)NE * 4);
  int*   permS  = (int*)alloc((size_t)NE * 4);
  int*   invp   = (int*)alloc((size_t)NE * 4);
  unsigned short* wT = (unsigned short*)alloc((size_t)140000 * 2);
  size_t used = (size_t)(p - (char*)d_ws);
  unsigned short* eaB = nullptr;
  if (ws_size >= used + (size_t)NE * 32 * 2 + 256)
    eaB = (unsigned short*)alloc((size_t)NE * 32 * 2);

  const int gN = (NN + 63) / 64;  // 1563
  const int gT = NT / 64;         // 3125
  const int gE = NE / 64;         // 15625

  // ---- CSR build ----
  hipMemsetAsync(cur, 0, (size_t)NN * sizeof(int), stream);
  hist_kernel<<<(NE + 255) / 256, 256, 0, stream>>>(ei, cur);
  blocksum_k<<<SCB, 256, 0, stream>>>(cur, bsum);
  scansums_k<<<1, 512, 0, stream>>>(bsum, rowptr);
  scatter_scan_k<<<SCB, 256, 0, stream>>>(cur, bsum, rowptr);
  hipMemsetAsync(cur, 0, (size_t)NN * sizeof(int), stream);
  fill_kernel<<<(NE + 255) / 256, 256, 0, stream>>>(ei, rowptr, cur, srcS, dstS, permS, invp);
  if (eaB)
    perm_eattr<<<(NE * 16 + 255) / 256, 256, 0, stream>>>(eattr, invp, eaB);

  // ---- weight prep ----
  PrepTab tb;
  int offs[14];
  int off = 0;
  auto set = [&](int s, const float* A, const float* B, int K, int C, int rows) {
    tb.a[s] = A; tb.b[s] = B; tb.K[s] = K; tb.C[s] = C; tb.rows[s] = rows;
    tb.off[s] = off; offs[s] = off; off += rows * 104;
  };
  set(0, node_w, nullptr, 64, 66, 80);
  set(1, edge_w, nullptr, 32, 66, 80);
  for (int l = 0; l < 2; l++) {
    set(2 + l, cw1 + (size_t)l * 4356, nullptr, 66, 66, 80);
    set(4 + l, cw2 + (size_t)l * 4356, nullptr, 66, 66, 80);
    set(6 + l, ew1 + (size_t)l * 13068 + 8712, nullptr, 66, 66, 80);       // W1c
    set(8 + l, ew2 + (size_t)l * 4356, nullptr, 66, 66, 80);
    set(10 + l, ew1 + (size_t)l * 13068, ew1 + (size_t)l * 13068 + 4356,   // W1a||W1b
        66, 66, 144);
  }
  set(12, mw1, mw1 + 3300, 66, 50, 112);   // A||B
  set(13, mw1 + 6600, nullptr, 66, 50, 80);  // C
  prep_w<<<14, 256, 0, stream>>>(tb, wT);

  // ---- embeds ----
  mfma_gemm<64, 2, 5, 66, 0, 4><<<gN, 256, 0, stream>>>(
      x, nullptr, wT + offs[0], node_b, h, hB, NN);
  mfma_gemm<32, 1, 5, 66, 0, 0><<<gT, 256, 0, stream>>>(
      tattr, nullptr, wT + offs[1], edge_b, tea, nullptr, NT);

  for (int l = 0; l < 2; l++) {
    // aggregation
    hipMemsetAsync(zbuf, 0, (size_t)NN * 66 * sizeof(float), stream);
    msg_aggr2<<<gE, 256, 0, stream>>>(rowptr, srcS, dstS, eaB, eattr, permS,
                                      wT + offs[1], edge_b, hB, zbuf);
    // node MLP: midb = bf16(relu((h+aggr)@cw1+b1)); z = midb@cw2+b2
    mfma_gemm<66, 3, 5, 66, 1, 3><<<gN, 256, 0, stream>>>(
        h, zbuf, wT + offs[2 + l], cb1 + l * 66, (unsigned short*)big, nullptr, NN);
    mfma_gemm<66, 3, 5, 66, 3, 0><<<gN, 256, 0, stream>>>(
        (unsigned short*)big, nullptr, wT + offs[4 + l], cb2 + l * 66, zbuf, nullptr, NN);
    // batchnorm + h update (refreshes hB mirror)
    hipMemsetAsync(stat, 0, 132 * sizeof(float), stream);
    bn_stats<<<(NN + 1023) / 1024, 256, 0, stream>>>(zbuf, stat);
    bn_update<<<(NN * 66 + 255) / 256, 256, 0, stream>>>(h, hB, zbuf, stat,
                                                         bng + l * 66, bnb + l * 66);
    // edge update: P12 = h @ [W1a||W1b] (one pass), then fused tile kernel
    mfma_gemm<66, 3, 9, 132, 0, 0><<<gN, 256, 0, stream>>>(
        h, nullptr, wT + offs[10 + l], nullptr, big, nullptr, NN);
    edge_fused2<<<gT, 256, 0, stream>>>(big, eli, wT + offs[6 + l], eb1 + l * 66,
                                        wT + offs[8 + l], eb2 + l * 66, tea);
  }

  // ---- final classifier ----
  mfma_gemm<66, 3, 7, 100, 2, 0><<<gN, 256, 0, stream>>>(
      h, nullptr, wT + offs[12], nullptr, big, nullptr, NN);
  final_fused2<<<gT, 256, 0, stream>>>(tea, big, eli, wT + offs[13], mb1,
                                       mw2, mb2, mw3, mb3, out);
}

// Round 6
// 1279.772 us; speedup vs baseline: 3.1675x; 1.0035x over previous
//
#include <hip/hip_runtime.h>

#define NN 100000   // nodes
#define NE 1000000  // edges (divisible by 64)
#define NT 200000   // target edges (divisible by 64)
#define SCB 391     // ceil(NN/256) scan blocks

typedef __attribute__((ext_vector_type(8))) short short8;
typedef __attribute__((ext_vector_type(4))) float f32x4;

__device__ __forceinline__ unsigned short f2b(float x) {  // fp32 -> bf16 RNE
  union { float f; unsigned int u; } v; v.f = x;
  unsigned int r = v.u + 0x7fffu + ((v.u >> 16) & 1u);
  return (unsigned short)(r >> 16);
}
__device__ __forceinline__ float b2f(unsigned short x) {
  union { unsigned int u; float f; } v; v.u = ((unsigned int)x) << 16;
  return v.f;
}

// ---------------------------------------------------------------------------
// Weight prep: up to two fp32 sources [K][C] -> bf16 transposed tile
// [rows][104]; row c<C from A col c, C<=c<2C from B col c-C, rest zero.
// ---------------------------------------------------------------------------
struct PrepTab {
  const float* a[14]; const float* b[14];
  int K[14], C[14], rows[14], off[14];
};

__global__ __launch_bounds__(256) void prep_w(PrepTab tab, unsigned short* wT) {
  int s = blockIdx.x;
  const float* A = tab.a[s];
  const float* B = tab.b[s];
  int K = tab.K[s], C = tab.C[s], rows = tab.rows[s];
  unsigned short* dst = wT + tab.off[s];
  int n = rows * 104;
  for (int i = threadIdx.x; i < n; i += 256) {
    int c = i / 104, k = i - c * 104;
    float v = 0.0f;
    if (k < K) {
      if (c < C) v = A[k * C + c];
      else if (B && c < 2 * C) v = B[k * C + (c - C)];
    }
    dst[i] = f2b(v);
  }
}

// ---------------------------------------------------------------------------
// Generic MFMA row-GEMM: out[R,C] = act(in (+add)) @ W + bias
// AIN: 0=f32, 1=f32+add, 2=relu(f32), 3=bf16 input.
// ROUT bit0=relu, bit1=bf16 out, bit2=also write bf16 mirror to out2.
// ---------------------------------------------------------------------------
template<int K, int KSTEPS, int CT, int C, int AIN, int ROUT>
__global__ __launch_bounds__(256) void mfma_gemm(
    const void* __restrict__ in, const float* __restrict__ add,
    const unsigned short* __restrict__ Bt, const float* __restrict__ bias,
    void* __restrict__ outp, void* __restrict__ out2, int R)
{
  constexpr int CR = CT * 16;
  __shared__ __align__(16) unsigned short As[64 * 104];
  __shared__ __align__(16) unsigned short Bs[CR * 104];
  __shared__ float bs[CR];
  const int t = threadIdx.x;
  const int r0 = blockIdx.x * 64;
  for (int i = t; i < CT * 208; i += 256) ((uint4*)Bs)[i] = ((const uint4*)Bt)[i];
  if (t < CR) bs[t] = (bias && t < C) ? bias[t] : 0.0f;
  constexpr int KH = KSTEPS * 16;  // float2 slots per row
  for (int i = t; i < 64 * KH; i += 256) {
    int r = i / KH, kk = (i - r * KH) * 2;
    int rg = r0 + r;
    unsigned short u0 = 0, u1 = 0;
    if (rg < R && kk < K) {
      if constexpr (AIN == 3) {
        unsigned int u = ((const unsigned int*)in)[((size_t)rg * K + kk) >> 1];
        u0 = u & 0xffffu; u1 = u >> 16;
      } else {
        float2 f = *(const float2*)((const float*)in + (size_t)rg * K + kk);
        float v0 = f.x, v1 = f.y;
        if constexpr (AIN == 1) {
          float2 g = *(const float2*)(add + (size_t)rg * K + kk);
          v0 += g.x; v1 += g.y;
        }
        if constexpr (AIN == 2) { v0 = fmaxf(v0, 0.f); v1 = fmaxf(v1, 0.f); }
        u0 = f2b(v0); u1 = f2b(v1);
      }
    }
    As[r * 104 + kk] = u0; As[r * 104 + kk + 1] = u1;
  }
  __syncthreads();
  const int lane = t & 63, w = t >> 6, m = lane & 15, q = lane >> 4;
  f32x4 acc[CT] = {};
  const unsigned short* Ap = As + (w * 16 + m) * 104 + q * 8;
  const unsigned short* Bp = Bs + m * 104 + q * 8;
#pragma unroll
  for (int ks = 0; ks < KSTEPS; ks++) {
    short8 a = *(const short8*)(Ap + ks * 32);
#pragma unroll
    for (int ct = 0; ct < CT; ct++) {
      short8 b = *(const short8*)(Bp + ct * 16 * 104 + ks * 32);
      acc[ct] = __builtin_amdgcn_mfma_f32_16x16x32_bf16(a, b, acc[ct], 0, 0, 0);
    }
  }
#pragma unroll
  for (int ct = 0; ct < CT; ct++) {
    int c = ct * 16 + m;
    if (c < C) {
      float bv = bs[c];
#pragma unroll
      for (int r2 = 0; r2 < 4; r2++) {
        int row = r0 + w * 16 + q * 4 + r2;
        if (row < R) {
          float v = acc[ct][r2] + bv;
          if constexpr ((ROUT & 1) != 0) v = fmaxf(v, 0.f);
          if constexpr ((ROUT & 2) != 0)
            ((unsigned short*)outp)[(size_t)row * C + c] = f2b(v);
          else
            ((float*)outp)[(size_t)row * C + c] = v;
          if constexpr ((ROUT & 4) != 0)
            ((unsigned short*)out2)[(size_t)row * C + c] = f2b(v);
        }
      }
    }
  }
}

// ---------------------------------------------------------------------------
// CSR build: histogram + 3-pass coalesced scan + fill
// ---------------------------------------------------------------------------
__global__ __launch_bounds__(256) void hist_kernel(const int* __restrict__ ei,
                                                   int* __restrict__ deg)
{
  int e = blockIdx.x * 256 + threadIdx.x;
  if (e < NE) atomicAdd(&deg[ei[NE + e]], 1);
}

__global__ __launch_bounds__(256) void blocksum_k(const int* __restrict__ deg,
                                                  int* __restrict__ bsum)
{
  __shared__ int red[256];
  const int t = threadIdx.x;
  int i = blockIdx.x * 256 + t;
  red[t] = (i < NN) ? deg[i] : 0;
  __syncthreads();
  for (int s = 128; s > 0; s >>= 1) {
    if (t < s) red[t] += red[t + s];
    __syncthreads();
  }
  if (t == 0) bsum[blockIdx.x] = red[0];
}

__global__ __launch_bounds__(512) void scansums_k(int* __restrict__ bsum,
                                                  int* __restrict__ rowptr)
{
  __shared__ int s[512];
  const int t = threadIdx.x;
  s[t] = (t < SCB) ? bsum[t] : 0;
  __syncthreads();
  for (int off = 1; off < 512; off <<= 1) {
    int v = (t >= off) ? s[t - off] : 0;
    __syncthreads();
    s[t] += v;
    __syncthreads();
  }
  if (t < SCB) bsum[t] = (t == 0) ? 0 : s[t - 1];  // exclusive
  if (t == 0) rowptr[NN] = NE;
}

__global__ __launch_bounds__(256) void scatter_scan_k(
    const int* __restrict__ deg, const int* __restrict__ bsum,
    int* __restrict__ rowptr)
{
  __shared__ int s[256];
  const int t = threadIdx.x;
  int i = blockIdx.x * 256 + t;
  int v = (i < NN) ? deg[i] : 0;
  s[t] = v;
  __syncthreads();
  for (int off = 1; off < 256; off <<= 1) {
    int x = (t >= off) ? s[t - off] : 0;
    __syncthreads();
    s[t] += x;
    __syncthreads();
  }
  if (i < NN) rowptr[i] = bsum[blockIdx.x] + s[t] - v;
}

__global__ __launch_bounds__(256) void fill_kernel(
    const int* __restrict__ ei, const int* __restrict__ rowptr,
    int* __restrict__ cur, int* __restrict__ srcS, int* __restrict__ dstS,
    int* __restrict__ permS, int* __restrict__ invp)
{
  int e = blockIdx.x * 256 + threadIdx.x;
  if (e >= NE) return;
  int d = ei[NE + e];
  int pos = atomicAdd(&cur[d], 1);
  int w = rowptr[d] + pos;
  srcS[w] = ei[e];
  dstS[w] = d;
  permS[w] = e;
  invp[e] = w;
}

// Linear-read, scatter-write permutation of edge_attr into dst-sorted bf16.
__global__ __launch_bounds__(256) void perm_eattr(
    const float* __restrict__ eattr, const int* __restrict__ invp,
    unsigned short* __restrict__ eaB)
{
  int i = blockIdx.x * 256 + threadIdx.x;  // over NE*16 float2 slots
  if (i >= NE * 16) return;
  int e = i >> 4, j = i & 15;
  float2 f = ((const float2*)eattr)[i];
  unsigned int packed = (unsigned int)f2b(f.x) | ((unsigned int)f2b(f.y) << 16);
  ((unsigned int*)eaB)[(size_t)invp[e] * 16 + j] = packed;
}

// ---------------------------------------------------------------------------
// One-time, layer-invariant: eaW[w] = edge_attr[perm[w]] @ edge_w + edge_b
// (dst-sorted, bf16). MFMA over 64-edge tiles.
// ---------------------------------------------------------------------------
__global__ __launch_bounds__(256) void eaw_kernel(
    const unsigned short* __restrict__ eaB, const float* __restrict__ eattr,
    const int* __restrict__ permS, const unsigned short* __restrict__ Bt,
    const float* __restrict__ bias, unsigned short* __restrict__ eaW)
{
  __shared__ __align__(16) unsigned short As[64 * 40];
  __shared__ __align__(16) unsigned short Bs[80 * 104];
  __shared__ float bs[80];
  const int t = threadIdx.x;
  const int e0 = blockIdx.x * 64;
  for (int i = t; i < 1040; i += 256) ((uint4*)Bs)[i] = ((const uint4*)Bt)[i];
  if (t < 80) bs[t] = (t < 66) ? bias[t] : 0.0f;
  if (eaB) {
    for (int i = t; i < 1024; i += 256) {
      int r = i >> 4, j = i & 15;
      unsigned int u = ((const unsigned int*)eaB)[(size_t)(e0 + r) * 16 + j];
      As[r * 40 + j * 2] = u & 0xffffu;
      As[r * 40 + j * 2 + 1] = u >> 16;
    }
  } else {
    for (int i = t; i < 1024; i += 256) {
      int r = i >> 4, j = i & 15;
      int p = permS[e0 + r];
      float2 f = ((const float2*)(eattr + (size_t)p * 32))[j];
      As[r * 40 + j * 2] = f2b(f.x);
      As[r * 40 + j * 2 + 1] = f2b(f.y);
    }
  }
  __syncthreads();
  const int lane = t & 63, w = t >> 6, m = lane & 15, q = lane >> 4;
  f32x4 acc[5] = {};
  short8 a = *(const short8*)(As + (w * 16 + m) * 40 + q * 8);
#pragma unroll
  for (int ct = 0; ct < 5; ct++) {
    short8 b = *(const short8*)(Bs + (ct * 16 + m) * 104 + q * 8);
    acc[ct] = __builtin_amdgcn_mfma_f32_16x16x32_bf16(a, b, acc[ct], 0, 0, 0);
  }
#pragma unroll
  for (int ct = 0; ct < 5; ct++) {
    int c = ct * 16 + m;
    if (c < 66) {
      float bv = bs[c];
#pragma unroll
      for (int r2 = 0; r2 < 4; r2++) {
        int e = w * 16 + q * 4 + r2;
        eaW[(size_t)(e0 + e) * 66 + c] = f2b(acc[ct][r2] + bv);
      }
    }
  }
}

// ---------------------------------------------------------------------------
// Per-layer aggregation, NO weights/MFMA: stream eaW (coalesced u32), add
// gathered hB row-u32s, relu -> LDS; run-parallel segmented sum.
// ---------------------------------------------------------------------------
__global__ __launch_bounds__(256) void msg_aggr3(
    const int* __restrict__ rowptr, const int* __restrict__ srcS,
    const int* __restrict__ dstS, const unsigned int* __restrict__ eaW32,
    const unsigned int* __restrict__ hB32, float* __restrict__ aggr)
{
  __shared__ float msgS[64 * 67];
  __shared__ int sidx[64], didx[64];
  __shared__ int runStart[65];
  __shared__ int nrunsS;
  const int t = threadIdx.x;
  const int e0 = blockIdx.x * 64;
  if (t < 64) { sidx[t] = srcS[e0 + t]; didx[t] = dstS[e0 + t]; }
  __syncthreads();
  if (t < 64) {  // run boundary detection (wave 0)
    bool b = (t == 0) || (didx[t] != didx[t - 1]);
    unsigned long long mask = __ballot(b);
    int idx = __popcll(mask & ((1ull << t) - 1ull));
    if (b) runStart[idx] = t;
    if (t == 63) { nrunsS = __popcll(mask); runStart[__popcll(mask)] = 64; }
  }
  for (int idx = t; idx < 64 * 33; idx += 256) {
    int e = idx / 33, j = idx - e * 33;
    unsigned int ua = eaW32[(size_t)e0 * 33 + idx];          // fully coalesced
    unsigned int uh = hB32[(size_t)sidx[e] * 33 + j];        // row-gather
    float v0 = b2f((unsigned short)(ua & 0xffffu)) + b2f((unsigned short)(uh & 0xffffu));
    float v1 = b2f((unsigned short)(ua >> 16)) + b2f((unsigned short)(uh >> 16));
    msgS[e * 67 + 2 * j]     = fmaxf(v0, 0.f);
    msgS[e * 67 + 2 * j + 1] = fmaxf(v1, 0.f);
  }
  __syncthreads();
  const int nr = nrunsS;
  for (int task = t; task < nr * 66; task += 256) {
    int r = task / 66, c = task - r * 66;
    int s0 = runStart[r], s1 = runStart[r + 1];
    float s = 0.0f;
    for (int e = s0; e < s1; e++) s += msgS[e * 67 + c];
    int n = didx[s0];
    bool partial = false;
    if (r == 0)      partial = (rowptr[n] < e0);
    if (r == nr - 1) partial = partial || (rowptr[n + 1] > e0 + 64);
    if (partial) atomicAdd(&aggr[(size_t)n * 66 + c], s);
    else         aggr[(size_t)n * 66 + c] = s;
  }
}

// ---------------------------------------------------------------------------
// Fallback (ws too small for eaW): R5's fused MFMA message+aggregate.
// ---------------------------------------------------------------------------
__global__ __launch_bounds__(256) void msg_aggr2(
    const int* __restrict__ rowptr, const int* __restrict__ srcS,
    const int* __restrict__ dstS, const unsigned short* __restrict__ eaB,
    const float* __restrict__ eattr, const int* __restrict__ permS,
    const unsigned short* __restrict__ Bt, const float* __restrict__ bias,
    const unsigned short* __restrict__ hB, float* __restrict__ aggr)
{
  __shared__ __align__(16) unsigned short As[64 * 40];
  __shared__ __align__(16) unsigned short Bs[80 * 104];
  __shared__ float msgS[64 * 67];
  __shared__ float bs[80];
  __shared__ int sidx[64], didx[64];
  __shared__ int runStart[65];
  __shared__ int nrunsS;
  const int t = threadIdx.x;
  const int e0 = blockIdx.x * 64;
  for (int i = t; i < 1040; i += 256) ((uint4*)Bs)[i] = ((const uint4*)Bt)[i];
  if (t < 80) bs[t] = (t < 66) ? bias[t] : 0.0f;
  if (t < 64) { sidx[t] = srcS[e0 + t]; didx[t] = dstS[e0 + t]; }
  if (eaB) {
    for (int i = t; i < 1024; i += 256) {
      int r = i >> 4, j = i & 15;
      unsigned int u = ((const unsigned int*)eaB)[(size_t)(e0 + r) * 16 + j];
      As[r * 40 + j * 2] = u & 0xffffu;
      As[r * 40 + j * 2 + 1] = u >> 16;
    }
  } else {
    for (int i = t; i < 1024; i += 256) {
      int r = i >> 4, j = i & 15;
      int p = permS[e0 + r];
      float2 f = ((const float2*)(eattr + (size_t)p * 32))[j];
      As[r * 40 + j * 2] = f2b(f.x);
      As[r * 40 + j * 2 + 1] = f2b(f.y);
    }
  }
  __syncthreads();
  if (t < 64) {
    bool b = (t == 0) || (didx[t] != didx[t - 1]);
    unsigned long long mask = __ballot(b);
    int idx = __popcll(mask & ((1ull << t) - 1ull));
    if (b) runStart[idx] = t;
    if (t == 63) { nrunsS = __popcll(mask); runStart[__popcll(mask)] = 64; }
  }
  const int lane = t & 63, w = t >> 6, m = lane & 15, q = lane >> 4;
  f32x4 acc[5] = {};
  short8 a = *(const short8*)(As + (w * 16 + m) * 40 + q * 8);
#pragma unroll
  for (int ct = 0; ct < 5; ct++) {
    short8 b = *(const short8*)(Bs + (ct * 16 + m) * 104 + q * 8);
    acc[ct] = __builtin_amdgcn_mfma_f32_16x16x32_bf16(a, b, acc[ct], 0, 0, 0);
  }
#pragma unroll
  for (int ct = 0; ct < 5; ct++) {
    int c = ct * 16 + m;
    if (c < 66) {
      float bv = bs[c];
#pragma unroll
      for (int r2 = 0; r2 < 4; r2++) {
        int e = w * 16 + q * 4 + r2;
        float v = acc[ct][r2] + bv + b2f(hB[(size_t)sidx[e] * 66 + c]);
        msgS[e * 67 + c] = fmaxf(v, 0.f);
      }
    }
  }
  __syncthreads();
  const int nr = nrunsS;
  for (int task = t; task < nr * 66; task += 256) {
    int r = task / 66, c = task - r * 66;
    int s0 = runStart[r], s1 = runStart[r + 1];
    float s = 0.0f;
    for (int e = s0; e < s1; e++) s += msgS[e * 67 + c];
    int n = didx[s0];
    bool partial = false;
    if (r == 0)      partial = (rowptr[n] < e0);
    if (r == nr - 1) partial = partial || (rowptr[n + 1] > e0 + 64);
    if (partial) atomicAdd(&aggr[(size_t)n * 66 + c], s);
    else         aggr[(size_t)n * 66 + c] = s;
  }
}

// ---------------------------------------------------------------------------
// BatchNorm stats + update (fp32); bn_update also refreshes hB mirror.
// ---------------------------------------------------------------------------
__global__ __launch_bounds__(256) void bn_stats(const float* __restrict__ z,
                                                float* __restrict__ stat)
{
  const int t = threadIdx.x;
  if (t >= 198) return;
  const int c = t % 66, rs = t / 66;
  const int r0 = blockIdx.x * 1024;
  float s1 = 0.0f, s2 = 0.0f;
  int rend = r0 + 1024; if (rend > NN) rend = NN;
  for (int r = r0 + rs; r < rend; r += 3) {
    float v = z[(size_t)r * 66 + c];
    s1 += v; s2 += v * v;
  }
  atomicAdd(&stat[c], s1);
  atomicAdd(&stat[66 + c], s2);
}

__global__ __launch_bounds__(256) void bn_update(
    float* __restrict__ h, unsigned short* __restrict__ hB,
    const float* __restrict__ z, const float* __restrict__ stat,
    const float* __restrict__ gamma, const float* __restrict__ beta)
{
  int idx = blockIdx.x * 256 + threadIdx.x;
  if (idx >= NN * 66) return;
  int c = idx % 66;
  float mean = stat[c] * (1.0f / NN);
  float var  = stat[66 + c] * (1.0f / NN) - mean * mean;
  float inv  = rsqrtf(var + 1e-5f);
  float zn   = (z[idx] - mean) * inv * gamma[c] + beta[c];
  float v = 0.5f * (h[idx] + fmaxf(zn, 0.0f));
  h[idx] = v;
  hB[idx] = f2b(v);
}

// ---------------------------------------------------------------------------
// Fused edge update (block = 64 target edges), MFMA chain:
//   mid = relu(tea@W1c + b1 + P12[ts,0:66] + P12[td,66:132]);   (P12 bf16)
//   tea += 0.5*(mid@W2 + b2)
// ---------------------------------------------------------------------------
__global__ __launch_bounds__(256) void edge_fused2(
    const unsigned short* __restrict__ P12, const int* __restrict__ eli,
    const unsigned short* __restrict__ B1t, const float* __restrict__ b1,
    const unsigned short* __restrict__ B2t, const float* __restrict__ b2,
    float* __restrict__ tea)
{
  __shared__ __align__(16) unsigned short As[64 * 104];  // tea tile, then mid
  __shared__ __align__(16) unsigned short Bs1[80 * 104];
  __shared__ __align__(16) unsigned short Bs2[80 * 104];
  __shared__ float b1s[80], b2s[80];
  __shared__ int sidx[64], didx[64];
  const int t = threadIdx.x;
  const int e0 = blockIdx.x * 64;
  for (int i = t; i < 1040; i += 256) {
    ((uint4*)Bs1)[i] = ((const uint4*)B1t)[i];
    ((uint4*)Bs2)[i] = ((const uint4*)B2t)[i];
  }
  if (t < 80) { b1s[t] = (t < 66) ? b1[t] : 0.f; b2s[t] = (t < 66) ? b2[t] : 0.f; }
  if (t < 64) { sidx[t] = eli[e0 + t]; didx[t] = eli[NT + e0 + t]; }
  for (int i = t; i < 64 * 48; i += 256) {
    int r = i / 48, kk = (i - r * 48) * 2;
    unsigned short u0 = 0, u1 = 0;
    if (kk < 66) {
      float2 f = *(const float2*)(tea + (size_t)(e0 + r) * 66 + kk);
      u0 = f2b(f.x); u1 = f2b(f.y);
    }
    As[r * 104 + kk] = u0; As[r * 104 + kk + 1] = u1;
  }
  __syncthreads();
  const int lane = t & 63, w = t >> 6, m = lane & 15, q = lane >> 4;
  const unsigned short* Ap = As + (w * 16 + m) * 104 + q * 8;
  const unsigned short* Bp1 = Bs1 + m * 104 + q * 8;
  f32x4 acc[5] = {};
#pragma unroll
  for (int ks = 0; ks < 3; ks++) {
    short8 a = *(const short8*)(Ap + ks * 32);
#pragma unroll
    for (int ct = 0; ct < 5; ct++) {
      short8 b = *(const short8*)(Bp1 + ct * 16 * 104 + ks * 32);
      acc[ct] = __builtin_amdgcn_mfma_f32_16x16x32_bf16(a, b, acc[ct], 0, 0, 0);
    }
  }
  __syncthreads();  // GEMM1 reads of As done before mid overwrite
#pragma unroll
  for (int ct = 0; ct < 5; ct++) {
    int c = ct * 16 + m;
    if (c < 66) {
      float bv = b1s[c];
#pragma unroll
      for (int r2 = 0; r2 < 4; r2++) {
        int e = w * 16 + q * 4 + r2;
        float v = acc[ct][r2] + bv + b2f(P12[(size_t)sidx[e] * 132 + c])
                                   + b2f(P12[(size_t)didx[e] * 132 + 66 + c]);
        As[e * 104 + c] = f2b(fmaxf(v, 0.f));
      }
    }
  }
  __syncthreads();
  const unsigned short* Bp2 = Bs2 + m * 104 + q * 8;
  f32x4 acc2[5] = {};
#pragma unroll
  for (int ks = 0; ks < 3; ks++) {
    short8 a = *(const short8*)(Ap + ks * 32);
#pragma unroll
    for (int ct = 0; ct < 5; ct++) {
      short8 b = *(const short8*)(Bp2 + ct * 16 * 104 + ks * 32);
      acc2[ct] = __builtin_amdgcn_mfma_f32_16x16x32_bf16(a, b, acc2[ct], 0, 0, 0);
    }
  }
#pragma unroll
  for (int ct = 0; ct < 5; ct++) {
    int c = ct * 16 + m;
    if (c < 66) {
      float bv = b2s[c];
#pragma unroll
      for (int r2 = 0; r2 < 4; r2++) {
        int e = w * 16 + q * 4 + r2;
        size_t idx = (size_t)(e0 + e) * 66 + c;
        tea[idx] += 0.5f * (acc2[ct][r2] + bv);
      }
    }
  }
}

// ---------------------------------------------------------------------------
// Fused final classifier (block = 64 target edges):
//   o1 = relu(tea@mw1c + b1 + P12f[ts,0:50] + P12f[td,50:100]);  (P12f bf16)
//   o2 = relu(o1@w2+b2); out = o2@w3+b3
// ---------------------------------------------------------------------------
__global__ __launch_bounds__(256) void final_fused2(
    const float* __restrict__ tea, const unsigned short* __restrict__ P12f,
    const int* __restrict__ eli, const unsigned short* __restrict__ B1t,
    const float* __restrict__ b1, const float* __restrict__ w2,
    const float* __restrict__ b2, const float* __restrict__ w3,
    const float* __restrict__ b3, float* __restrict__ out)
{
  __shared__ __align__(16) unsigned short As[64 * 104];
  __shared__ __align__(16) unsigned short Bs[64 * 104];
  __shared__ float o1s[64 * 51];
  __shared__ float o2s[64 * 25];
  __shared__ float w2s[50 * 25], w3s[50];
  __shared__ float b1s[64], b2s[25], b3s[2];
  __shared__ int sidx[64], didx[64];
  const int t = threadIdx.x;
  const int e0 = blockIdx.x * 64;
  for (int i = t; i < 832; i += 256) ((uint4*)Bs)[i] = ((const uint4*)B1t)[i];
  for (int i = t; i < 50 * 25; i += 256) w2s[i] = w2[i];
  if (t < 50) w3s[t] = w3[t];
  if (t < 64) { b1s[t] = (t < 50) ? b1[t] : 0.f; sidx[t] = eli[e0 + t]; didx[t] = eli[NT + e0 + t]; }
  if (t < 25) b2s[t] = b2[t];
  if (t < 2)  b3s[t] = b3[t];
  for (int i = t; i < 64 * 48; i += 256) {
    int r = i / 48, kk = (i - r * 48) * 2;
    unsigned short u0 = 0, u1 = 0;
    if (kk < 66) {
      float2 f = *(const float2*)(tea + (size_t)(e0 + r) * 66 + kk);
      u0 = f2b(f.x); u1 = f2b(f.y);
    }
    As[r * 104 + kk] = u0; As[r * 104 + kk + 1] = u1;
  }
  __syncthreads();
  const int lane = t & 63, w = t >> 6, m = lane & 15, q = lane >> 4;
  const unsigned short* Ap = As + (w * 16 + m) * 104 + q * 8;
  const unsigned short* Bp = Bs + m * 104 + q * 8;
  f32x4 acc[4] = {};
#pragma unroll
  for (int ks = 0; ks < 3; ks++) {
    short8 a = *(const short8*)(Ap + ks * 32);
#pragma unroll
    for (int ct = 0; ct < 4; ct++) {
      short8 b = *(const short8*)(Bp + ct * 16 * 104 + ks * 32);
      acc[ct] = __builtin_amdgcn_mfma_f32_16x16x32_bf16(a, b, acc[ct], 0, 0, 0);
    }
  }
#pragma unroll
  for (int ct = 0; ct < 4; ct++) {
    int c = ct * 16 + m;
    if (c < 50) {
      float bv = b1s[c];
#pragma unroll
      for (int r2 = 0; r2 < 4; r2++) {
        int e = w * 16 + q * 4 + r2;
        float v = acc[ct][r2] + bv + b2f(P12f[(size_t)sidx[e] * 100 + c])
                                   + b2f(P12f[(size_t)didx[e] * 100 + 50 + c]);
        o1s[e * 51 + c] = fmaxf(v, 0.f);
      }
    }
  }
  __syncthreads();
  for (int it = t; it < 64 * 25; it += 256) {
    int e = it / 25, c = it - e * 25;
    float s = b2s[c];
    for (int k = 0; k < 50; k++) s = fmaf(o1s[e * 51 + k], w2s[k * 25 + c], s);
    o2s[e * 25 + c] = fmaxf(s, 0.f);
  }
  __syncthreads();
  if (t < 128) {
    int e = t >> 1, c = t & 1;
    float s = b3s[c];
    for (int k = 0; k < 25; k++) s = fmaf(o2s[e * 25 + k], w3s[k * 2 + c], s);
    out[(size_t)(e0 + e) * 2 + c] = s;
  }
}

// ---------------------------------------------------------------------------
extern "C" void kernel_launch(void* const* d_in, const int* in_sizes, int n_in,
                              void* d_out, int out_size, void* d_ws, size_t ws_size,
                              hipStream_t stream) {
  const float* x      = (const float*)d_in[0];
  const int*   ei     = (const int*)  d_in[1];
  const float* eattr  = (const float*)d_in[2];
  const int*   eli    = (const int*)  d_in[3];
  const float* tattr  = (const float*)d_in[4];
  const float* node_w = (const float*)d_in[5];
  const float* node_b = (const float*)d_in[6];
  const float* edge_w = (const float*)d_in[7];
  const float* edge_b = (const float*)d_in[8];
  const float* cw1    = (const float*)d_in[9];
  const float* cb1    = (const float*)d_in[10];
  const float* cw2    = (const float*)d_in[11];
  const float* cb2    = (const float*)d_in[12];
  const float* bng    = (const float*)d_in[13];
  const float* bnb    = (const float*)d_in[14];
  const float* ew1    = (const float*)d_in[15];
  const float* eb1    = (const float*)d_in[16];
  const float* ew2    = (const float*)d_in[17];
  const float* eb2    = (const float*)d_in[18];
  const float* mw1    = (const float*)d_in[19];
  const float* mb1    = (const float*)d_in[20];
  const float* mw2    = (const float*)d_in[21];
  const float* mb2    = (const float*)d_in[22];
  const float* mw3    = (const float*)d_in[23];
  const float* mb3    = (const float*)d_in[24];
  float* out = (float*)d_out;

  // ---- workspace layout (optional eaW, eaB last) ----
  char* p = (char*)d_ws;
  auto alloc = [&](size_t bytes) { void* r = p; p += (bytes + 255) & ~(size_t)255; return r; };
  float* h      = (float*)alloc((size_t)NN * 66 * 4);
  unsigned short* hB = (unsigned short*)alloc((size_t)NN * 66 * 2);
  float* big    = (float*)alloc((size_t)NN * 132 * 4);  // P12(bf16) / midb
  float* zbuf   = (float*)alloc((size_t)NN * 66 * 4);   // aggr / z
  float* tea    = (float*)alloc((size_t)NT * 66 * 4);
  float* stat   = (float*)alloc(1024);
  int*   rowptr = (int*)alloc((NN + 1) * 4);
  int*   cur    = (int*)alloc((size_t)NN * 4);
  int*   bsum   = (int*)alloc((SCB + 1) * 4);
  int*   srcS   = (int*)alloc((size_t)NE * 4);
  int*   dstS   = (int*)alloc((size_t)NE * 4);
  int*   permS  = (int*)alloc((size_t)NE * 4);
  int*   invp   = (int*)alloc((size_t)NE * 4);
  unsigned short* wT = (unsigned short*)alloc((size_t)140000 * 2);
  size_t used = (size_t)(p - (char*)d_ws);
  unsigned short* eaW = nullptr;
  if (ws_size >= used + (size_t)NE * 66 * 2 + 256)
    eaW = (unsigned short*)alloc((size_t)NE * 66 * 2);
  used = (size_t)(p - (char*)d_ws);
  unsigned short* eaB = nullptr;
  if (ws_size >= used + (size_t)NE * 32 * 2 + 256)
    eaB = (unsigned short*)alloc((size_t)NE * 32 * 2);

  const int gN = (NN + 63) / 64;  // 1563
  const int gT = NT / 64;         // 3125
  const int gE = NE / 64;         // 15625

  // ---- CSR build ----
  hipMemsetAsync(cur, 0, (size_t)NN * sizeof(int), stream);
  hist_kernel<<<(NE + 255) / 256, 256, 0, stream>>>(ei, cur);
  blocksum_k<<<SCB, 256, 0, stream>>>(cur, bsum);
  scansums_k<<<1, 512, 0, stream>>>(bsum, rowptr);
  scatter_scan_k<<<SCB, 256, 0, stream>>>(cur, bsum, rowptr);
  hipMemsetAsync(cur, 0, (size_t)NN * sizeof(int), stream);
  fill_kernel<<<(NE + 255) / 256, 256, 0, stream>>>(ei, rowptr, cur, srcS, dstS, permS, invp);
  if (eaB)
    perm_eattr<<<(NE * 16 + 255) / 256, 256, 0, stream>>>(eattr, invp, eaB);

  // ---- weight prep ----
  PrepTab tb;
  int offs[14];
  int off = 0;
  auto set = [&](int s, const float* A, const float* B, int K, int C, int rows) {
    tb.a[s] = A; tb.b[s] = B; tb.K[s] = K; tb.C[s] = C; tb.rows[s] = rows;
    tb.off[s] = off; offs[s] = off; off += rows * 104;
  };
  set(0, node_w, nullptr, 64, 66, 80);
  set(1, edge_w, nullptr, 32, 66, 80);
  for (int l = 0; l < 2; l++) {
    set(2 + l, cw1 + (size_t)l * 4356, nullptr, 66, 66, 80);
    set(4 + l, cw2 + (size_t)l * 4356, nullptr, 66, 66, 80);
    set(6 + l, ew1 + (size_t)l * 13068 + 8712, nullptr, 66, 66, 80);       // W1c
    set(8 + l, ew2 + (size_t)l * 4356, nullptr, 66, 66, 80);
    set(10 + l, ew1 + (size_t)l * 13068, ew1 + (size_t)l * 13068 + 4356,   // W1a||W1b
        66, 66, 144);
  }
  set(12, mw1, mw1 + 3300, 66, 50, 112);   // A||B
  set(13, mw1 + 6600, nullptr, 66, 50, 80);  // C
  prep_w<<<14, 256, 0, stream>>>(tb, wT);

  // ---- one-time, layer-invariant ea projection ----
  if (eaW)
    eaw_kernel<<<gE, 256, 0, stream>>>(eaB, eattr, permS, wT + offs[1], edge_b, eaW);

  // ---- embeds ----
  mfma_gemm<64, 2, 5, 66, 0, 4><<<gN, 256, 0, stream>>>(
      x, nullptr, wT + offs[0], node_b, h, hB, NN);
  mfma_gemm<32, 1, 5, 66, 0, 0><<<gT, 256, 0, stream>>>(
      tattr, nullptr, wT + offs[1], edge_b, tea, nullptr, NT);

  for (int l = 0; l < 2; l++) {
    // aggregation
    hipMemsetAsync(zbuf, 0, (size_t)NN * 66 * sizeof(float), stream);
    if (eaW)
      msg_aggr3<<<gE, 256, 0, stream>>>(rowptr, srcS, dstS,
                                        (const unsigned int*)eaW,
                                        (const unsigned int*)hB, zbuf);
    else
      msg_aggr2<<<gE, 256, 0, stream>>>(rowptr, srcS, dstS, eaB, eattr, permS,
                                        wT + offs[1], edge_b, hB, zbuf);
    // node MLP: midb = bf16(relu((h+aggr)@cw1+b1)); z = midb@cw2+b2
    mfma_gemm<66, 3, 5, 66, 1, 3><<<gN, 256, 0, stream>>>(
        h, zbuf, wT + offs[2 + l], cb1 + l * 66, (unsigned short*)big, nullptr, NN);
    mfma_gemm<66, 3, 5, 66, 3, 0><<<gN, 256, 0, stream>>>(
        (unsigned short*)big, nullptr, wT + offs[4 + l], cb2 + l * 66, zbuf, nullptr, NN);
    // batchnorm + h update (refreshes hB mirror)
    hipMemsetAsync(stat, 0, 132 * sizeof(float), stream);
    bn_stats<<<(NN + 1023) / 1024, 256, 0, stream>>>(zbuf, stat);
    bn_update<<<(NN * 66 + 255) / 256, 256, 0, stream>>>(h, hB, zbuf, stat,
                                                         bng + l * 66, bnb + l * 66);
    // edge update: P12 = bf16(h @ [W1a||W1b]), then fused tile kernel
    mfma_gemm<66, 3, 9, 132, 0, 2><<<gN, 256, 0, stream>>>(
        h, nullptr, wT + offs[10 + l], nullptr, big, nullptr, NN);
    edge_fused2<<<gT, 256, 0, stream>>>((const unsigned short*)big, eli,
                                        wT + offs[6 + l], eb1 + l * 66,
                                        wT + offs[8 + l], eb2 + l * 66, tea);
  }

  // ---- final classifier ----
  mfma_gemm<66, 3, 7, 100, 2, 2><<<gN, 256, 0, stream>>>(
      h, nullptr, wT + offs[12], nullptr, big, nullptr, NN);
  final_fused2<<<gT, 256, 0, stream>>>(tea, (const unsigned short*)big, eli,
                                       wT + offs[13], mb1,
                                       mw2, mb2, mw3, mb3, out);
}